// Round 10
// baseline (505.196 us; speedup 1.0000x reference)
//
#include <hip/hip_runtime.h>

#define NN 50000
#define NE 800000
#define NG 512
#define TPB 256
#define BN_EPS 1e-5f
#define NBLK_G 784      // GEMM grid: ceil(NN/64)=782, padded to 784 so finalize
                        // trip count is a compile-time constant
#define EDGE_BLKS 3125  // NE/TPB exactly
#define TPB_FIN 512

__device__ __forceinline__ float bf2f(unsigned u) {  // low 16 bits = bf16
  return __uint_as_float(u << 16);
}
__device__ __forceinline__ unsigned f2bf(float f) {
  unsigned u = __float_as_uint(f);
  u += 0x7FFFu + ((u >> 16) & 1u);  // round-to-nearest-even
  return u >> 16;
}

__global__ void k_zero(int* __restrict__ p, int n) {
  int i = blockIdx.x * TPB + threadIdx.x;
  if (i < n) p[i] = 0;
}

__global__ void k_hist(const int* __restrict__ dst, int* __restrict__ counts) {
  int e = blockIdx.x * TPB + threadIdx.x;
  if (e < NE) atomicAdd(&counts[dst[e]], 1);
}

__global__ void k_scan1(const int* __restrict__ counts, int* __restrict__ incl,
                        int* __restrict__ btot) {
  __shared__ int lds[TPB];
  int i = blockIdx.x * TPB + threadIdx.x;
  int v = (i < NN) ? counts[i] : 0;
  lds[threadIdx.x] = v;
  __syncthreads();
  for (int off = 1; off < TPB; off <<= 1) {
    int t = (threadIdx.x >= off) ? lds[threadIdx.x - off] : 0;
    __syncthreads();
    lds[threadIdx.x] += t;
    __syncthreads();
  }
  if (i < NN) incl[i] = lds[threadIdx.x];
  if (threadIdx.x == TPB - 1) btot[blockIdx.x] = lds[TPB - 1];
}

__global__ void k_scan2(int* __restrict__ btot, int nb) {
  __shared__ int lds[TPB];
  int t = (threadIdx.x < nb) ? btot[threadIdx.x] : 0;
  int own = t;
  lds[threadIdx.x] = t;
  __syncthreads();
  for (int off = 1; off < TPB; off <<= 1) {
    int u = (threadIdx.x >= off) ? lds[threadIdx.x - off] : 0;
    __syncthreads();
    lds[threadIdx.x] += u;
    __syncthreads();
  }
  btot[threadIdx.x] = lds[threadIdx.x] - own;
}

__global__ void k_scan3(const int* __restrict__ incl, const int* __restrict__ btot,
                        int* __restrict__ row_ptr) {
  int i = blockIdx.x * TPB + threadIdx.x;
  if (i == 0) row_ptr[0] = 0;
  if (i < NN) row_ptr[i + 1] = incl[i] + btot[i >> 8];
}

// counting-sort fill; srcs stored as ushort (NN < 2^16) to halve the
// partial-line scatter write amplification (r9: 55.7MB HBM writes for 3.2MB).
__global__ void k_fill(const int* __restrict__ src, const int* __restrict__ dst,
                       const int* __restrict__ row_ptr, int* __restrict__ fill_pos,
                       unsigned short* __restrict__ srcs) {
  int e = blockIdx.x * TPB + threadIdx.x;  // EDGE_BLKS*TPB == NE exactly
  int d = dst[e];
  int pos = row_ptr[d] + atomicAdd(&fill_pos[d], 1);
  srcs[pos] = (unsigned short)src[e];
}

// h_bf[n] = bf16(emb[x[n]]) — layer-0 gather source (packed bf16 pairs)
__global__ void k_embed_bf(const int* __restrict__ x, const float* __restrict__ emb,
                           unsigned* __restrict__ h_bf) {
  int i = blockIdx.x * TPB + threadIdx.x;
  if (i >= NN * 32) return;
  int n = i >> 5, l = i & 31;
  float2 ev = *(const float2*)&emb[x[n] * 64 + 2 * l];
  h_bf[i] = f2bf(ev.x) | (f2bf(ev.y) << 16);
}

// Aggregate over bf16 h (all 4 layers), optional BN affine of prev layer:
//   z = sc*(h_self + sum h_src) + (1+deg)*sh   -> packed bf16
// Wave per node; 32 lanes x 2 features; halves take even/odd edges,
// shfl_xor(32) combines.
template <bool BN>
__global__ void k_aggregate_bf(const unsigned* __restrict__ h_bf,
                               const int* __restrict__ row_ptr,
                               const unsigned short* __restrict__ srcs,
                               const float* __restrict__ bnst,
                               unsigned* __restrict__ zb) {
  int wid = (blockIdx.x * TPB + threadIdx.x) >> 6;
  int lane = threadIdx.x & 63;
  if (wid >= NN) return;
  int half = lane >> 5, l = lane & 31;
  int beg = row_ptr[wid], end = row_ptr[wid + 1];
  float a0 = 0.f, a1 = 0.f;
  if (half == 0) {
    unsigned u = h_bf[(size_t)wid * 32 + l];
    a0 = bf2f(u & 0xFFFF);
    a1 = bf2f(u >> 16);
  }
  int e = beg + half;
  for (; e + 6 < end; e += 8) {
    int s0 = srcs[e], s1 = srcs[e + 2], s2 = srcs[e + 4], s3 = srcs[e + 6];
    unsigned u0 = h_bf[(size_t)s0 * 32 + l];
    unsigned u1 = h_bf[(size_t)s1 * 32 + l];
    unsigned u2 = h_bf[(size_t)s2 * 32 + l];
    unsigned u3 = h_bf[(size_t)s3 * 32 + l];
    a0 += (bf2f(u0 & 0xFFFF) + bf2f(u1 & 0xFFFF)) +
          (bf2f(u2 & 0xFFFF) + bf2f(u3 & 0xFFFF));
    a1 += (bf2f(u0 >> 16) + bf2f(u1 >> 16)) + (bf2f(u2 >> 16) + bf2f(u3 >> 16));
  }
  for (; e < end; e += 2) {
    unsigned u = h_bf[(size_t)srcs[e] * 32 + l];
    a0 += bf2f(u & 0xFFFF);
    a1 += bf2f(u >> 16);
  }
  a0 += __shfl_xor(a0, 32);
  a1 += __shfl_xor(a1, 32);
  if (half == 0) {
    float zv0, zv1;
    if constexpr (BN) {
      float2 scv = *(const float2*)&bnst[2 * l];
      float2 shv = *(const float2*)&bnst[64 + 2 * l];
      float d1 = (float)(1 + end - beg);
      zv0 = fmaf(scv.x, a0, d1 * shv.x);
      zv1 = fmaf(scv.y, a1, d1 * shv.y);
    } else {
      zv0 = a0;
      zv1 = a1;
    }
    zb[(size_t)wid * 32 + l] = f2bf(zv0) | (f2bf(zv1) << 16);
  }
}

// GEMM1: z2[N,128] = z[N,64] @ W[64,128] + b1 (z bf16 in, z2 bf16 out),
// with per-block f32 column stats of z2.
__global__ __launch_bounds__(TPB) void k_gemm1(const unsigned short* __restrict__ zb,
                                               const float* __restrict__ W,
                                               const float* __restrict__ bias,
                                               unsigned short* __restrict__ z2b,
                                               float* __restrict__ partials) {
  constexpr int K = 64, NC = 128, LDA = 68;
  constexpr int TX = 32, TY = 8, RT = 8;
  __shared__ float Al[64 * LDA];
  __shared__ float Wl[K * NC];
  const int t = threadIdx.x;
  const int r0 = blockIdx.x * 64;

  {
    const float4* Wg = (const float4*)W;
    float4* Wl4 = (float4*)Wl;
#pragma unroll
    for (int j = 0; j < (K * NC / 4) / TPB; ++j) Wl4[t + j * TPB] = Wg[t + j * TPB];
  }
#pragma unroll
  for (int j = 0; j < 4; ++j) {
    int qi = t + j * TPB;
    int row = qi >> 4, cq = qi & 15;
    int r = r0 + row;
    float4 v = make_float4(0.f, 0.f, 0.f, 0.f);
    if (r < NN) {
      uint2 u = *(const uint2*)&zb[(size_t)r * 64 + cq * 4];
      v = make_float4(bf2f(u.x & 0xFFFF), bf2f(u.x >> 16), bf2f(u.y & 0xFFFF),
                      bf2f(u.y >> 16));
    }
    *(float4*)&Al[row * LDA + cq * 4] = v;
  }
  __syncthreads();

  const int tx = t % TX, ty = t / TX;
  const int c0 = tx * 4;
  float4 b0 = *(const float4*)&bias[c0];
  float acc[RT][4];
#pragma unroll
  for (int i = 0; i < RT; ++i) {
    acc[i][0] = b0.x; acc[i][1] = b0.y; acc[i][2] = b0.z; acc[i][3] = b0.w;
  }
  const float* Ab = &Al[ty * RT * LDA];
#pragma unroll 4
  for (int k4 = 0; k4 < K / 4; ++k4) {
    float4 a[RT];
#pragma unroll
    for (int i = 0; i < RT; ++i) a[i] = *(const float4*)&Ab[i * LDA + k4 * 4];
#pragma unroll
    for (int kk = 0; kk < 4; ++kk) {
      float4 b = *(const float4*)&Wl[(k4 * 4 + kk) * NC + c0];
#pragma unroll
      for (int i = 0; i < RT; ++i) {
        float av = (&a[i].x)[kk];
        acc[i][0] = fmaf(av, b.x, acc[i][0]);
        acc[i][1] = fmaf(av, b.y, acc[i][1]);
        acc[i][2] = fmaf(av, b.z, acc[i][2]);
        acc[i][3] = fmaf(av, b.w, acc[i][3]);
      }
    }
  }
  float s[4] = {0.f, 0.f, 0.f, 0.f}, q[4] = {0.f, 0.f, 0.f, 0.f};
#pragma unroll
  for (int i = 0; i < RT; ++i) {
    int r = r0 + ty * RT + i;
    if (r < NN) {
      uint2 o;
      o.x = f2bf(acc[i][0]) | (f2bf(acc[i][1]) << 16);
      o.y = f2bf(acc[i][2]) | (f2bf(acc[i][3]) << 16);
      *(uint2*)&z2b[(size_t)r * NC + c0] = o;
      s[0] += acc[i][0]; q[0] += acc[i][0] * acc[i][0];
      s[1] += acc[i][1]; q[1] += acc[i][1] * acc[i][1];
      s[2] += acc[i][2]; q[2] += acc[i][2] * acc[i][2];
      s[3] += acc[i][3]; q[3] += acc[i][3] * acc[i][3];
    }
  }
  __syncthreads();
  float* Sl = Al;  // 2*TY*NC = 2048 floats
#pragma unroll
  for (int j = 0; j < 4; ++j) {
    Sl[ty * NC + c0 + j] = s[j];
    Sl[TY * NC + ty * NC + c0 + j] = q[j];
  }
  __syncthreads();
  if (t < NC) {
    float ss = 0.f, qq = 0.f;
#pragma unroll
    for (int g = 0; g < TY; ++g) {
      ss += Sl[g * NC + t];
      qq += Sl[TY * NC + g * NC + t];
    }
    partials[blockIdx.x * 2 * NC + t] = ss;
    partials[blockIdx.x * 2 * NC + NC + t] = qq;
  }
}

// GEMM2: h[N,64] = relu( relu(bn1(z2)) @ W[128,64] + b2 ), z2 bf16 in,
// h always packed bf16 out (gather/pool source).
template <bool STATS>
__global__ __launch_bounds__(TPB) void k_gemm2(const unsigned short* __restrict__ z2b,
                                               const float* __restrict__ W,
                                               const float* __restrict__ bias,
                                               const float* __restrict__ bnst,
                                               unsigned short* __restrict__ outp,
                                               float* __restrict__ partials) {
  constexpr int K = 128, NC = 64, LDA = 128;
  constexpr int TX = 16, TY = 16, RT = 4;
  __shared__ float Al[64 * LDA];
  __shared__ float Wl[K * NC];
  const int t = threadIdx.x;
  const int r0 = blockIdx.x * 64;

  {
    const float4* Wg = (const float4*)W;
    float4* Wl4 = (float4*)Wl;
#pragma unroll
    for (int j = 0; j < (K * NC / 4) / TPB; ++j) Wl4[t + j * TPB] = Wg[t + j * TPB];
  }
  {
    int cq = t & 15, rb = t >> 4;  // 16 col-groups of 8, 16 row-lanes
    float4 scA = *(const float4*)&bnst[cq * 8];
    float4 scB = *(const float4*)&bnst[cq * 8 + 4];
    float4 shA = *(const float4*)&bnst[K + cq * 8];
    float4 shB = *(const float4*)&bnst[K + cq * 8 + 4];
#pragma unroll
    for (int j = 0; j < 4; ++j) {
      int row = rb + j * 16;
      int r = r0 + row;
      float4 vA = make_float4(0.f, 0.f, 0.f, 0.f), vB = vA;
      if (r < NN) {
        uint4 u = *(const uint4*)&z2b[(size_t)r * 128 + cq * 8];
        vA = make_float4(bf2f(u.x & 0xFFFF), bf2f(u.x >> 16), bf2f(u.y & 0xFFFF),
                         bf2f(u.y >> 16));
        vB = make_float4(bf2f(u.z & 0xFFFF), bf2f(u.z >> 16), bf2f(u.w & 0xFFFF),
                         bf2f(u.w >> 16));
        vA.x = fmaxf(fmaf(vA.x, scA.x, shA.x), 0.f);
        vA.y = fmaxf(fmaf(vA.y, scA.y, shA.y), 0.f);
        vA.z = fmaxf(fmaf(vA.z, scA.z, shA.z), 0.f);
        vA.w = fmaxf(fmaf(vA.w, scA.w, shA.w), 0.f);
        vB.x = fmaxf(fmaf(vB.x, scB.x, shB.x), 0.f);
        vB.y = fmaxf(fmaf(vB.y, scB.y, shB.y), 0.f);
        vB.z = fmaxf(fmaf(vB.z, scB.z, shB.z), 0.f);
        vB.w = fmaxf(fmaf(vB.w, scB.w, shB.w), 0.f);
      }
      *(float4*)&Al[row * LDA + cq * 8] = vA;
      *(float4*)&Al[row * LDA + cq * 8 + 4] = vB;
    }
  }
  __syncthreads();

  const int tx = t % TX, ty = t / TX;
  const int c0 = tx * 4;
  float4 b0 = *(const float4*)&bias[c0];
  float acc[RT][4];
#pragma unroll
  for (int i = 0; i < RT; ++i) {
    acc[i][0] = b0.x; acc[i][1] = b0.y; acc[i][2] = b0.z; acc[i][3] = b0.w;
  }
  const float* Ab = &Al[ty * RT * LDA];
#pragma unroll 4
  for (int k4 = 0; k4 < K / 4; ++k4) {
    float4 a[RT];
#pragma unroll
    for (int i = 0; i < RT; ++i) a[i] = *(const float4*)&Ab[i * LDA + k4 * 4];
#pragma unroll
    for (int kk = 0; kk < 4; ++kk) {
      float4 b = *(const float4*)&Wl[(k4 * 4 + kk) * NC + c0];
#pragma unroll
      for (int i = 0; i < RT; ++i) {
        float av = (&a[i].x)[kk];
        acc[i][0] = fmaf(av, b.x, acc[i][0]);
        acc[i][1] = fmaf(av, b.y, acc[i][1]);
        acc[i][2] = fmaf(av, b.z, acc[i][2]);
        acc[i][3] = fmaf(av, b.w, acc[i][3]);
      }
    }
  }
  float s[4] = {0.f, 0.f, 0.f, 0.f}, q[4] = {0.f, 0.f, 0.f, 0.f};
#pragma unroll
  for (int i = 0; i < RT; ++i) {
    int r = r0 + ty * RT + i;
    if (r < NN) {
      float ox = fmaxf(acc[i][0], 0.f), oy = fmaxf(acc[i][1], 0.f);
      float oz = fmaxf(acc[i][2], 0.f), ow = fmaxf(acc[i][3], 0.f);
      uint2 o;
      o.x = f2bf(ox) | (f2bf(oy) << 16);
      o.y = f2bf(oz) | (f2bf(ow) << 16);
      *(uint2*)&outp[(size_t)r * NC + c0] = o;
      if constexpr (STATS) {
        s[0] += ox; q[0] += ox * ox;
        s[1] += oy; q[1] += oy * oy;
        s[2] += oz; q[2] += oz * oz;
        s[3] += ow; q[3] += ow * ow;
      }
    }
  }
  if constexpr (STATS) {
    __syncthreads();
    float* Sl = Al;
#pragma unroll
    for (int j = 0; j < 4; ++j) {
      Sl[ty * NC + c0 + j] = s[j];
      Sl[TY * NC + ty * NC + c0 + j] = q[j];
    }
    __syncthreads();
    if (t < NC) {
      float ss = 0.f, qq = 0.f;
#pragma unroll
      for (int g = 0; g < TY; ++g) {
        ss += Sl[g * NC + t];
        qq += Sl[TY * NC + g * NC + t];
      }
      partials[blockIdx.x * 2 * NC + t] = ss;
      partials[blockIdx.x * 2 * NC + NC + t] = qq;
    }
  }
}

// Fold partials: constant trip count + unroll-8 (r8 fix), LDS tree-fold.
template <int C>
__global__ __launch_bounds__(TPB_FIN) void k_finalize(const float* __restrict__ partials,
                                                      const float* __restrict__ gamma,
                                                      const float* __restrict__ beta,
                                                      float* __restrict__ out) {
  constexpr int G = TPB_FIN / C;
  constexpr int IT = NBLK_G / G;
  __shared__ float lds[2 * TPB_FIN];
  const int c = threadIdx.x % C, g = threadIdx.x / C;
  const float* p = partials + g * 2 * C + c;
  float s = 0.f, s2 = 0.f;
#pragma unroll 8
  for (int bb = 0; bb < IT; ++bb) {
    s += p[(size_t)bb * G * 2 * C];
    s2 += p[(size_t)bb * G * 2 * C + C];
  }
  lds[threadIdx.x] = s;
  lds[TPB_FIN + threadIdx.x] = s2;
  __syncthreads();
  if (g == 0) {
#pragma unroll
    for (int k = 1; k < G; ++k) {
      s += lds[k * C + c];
      s2 += lds[TPB_FIN + k * C + c];
    }
    float invN = 1.0f / NN;
    float mu = s * invN;
    float var = s2 * invN - mu * mu;
    float rs = rsqrtf(var + BN_EPS) * gamma[c];
    out[c] = rs;
    out[C + c] = beta[c] - mu * rs;
  }
}

// one BLOCK per graph over bf16 h: thread = (row-group, uint column);
// 8 row-groups stride the contiguous row range, LDS-reduce.
__global__ void k_poolseg_bf(const unsigned* __restrict__ h_bf,
                             const int* __restrict__ batch, float* __restrict__ g) {
  __shared__ float lds[2 * TPB];
  int gi = blockIdx.x;
  int col = threadIdx.x & 31, grp = threadIdx.x >> 5;  // 8 groups
  int a = 0, b = NN;
  while (a < b) { int m = (a + b) >> 1; if (batch[m] < gi) a = m + 1; else b = m; }
  int lo = a;
  b = NN;
  while (a < b) { int m = (a + b) >> 1; if (batch[m] < gi + 1) a = m + 1; else b = m; }
  int hi = a;
  float a0 = 0.f, a1 = 0.f;
  for (int n = lo + grp; n < hi; n += 8) {
    unsigned u = h_bf[(size_t)n * 32 + col];
    a0 += bf2f(u & 0xFFFF);
    a1 += bf2f(u >> 16);
  }
  lds[threadIdx.x] = a0;
  lds[TPB + threadIdx.x] = a1;
  __syncthreads();
  if (grp == 0) {
#pragma unroll
    for (int k = 1; k < 8; ++k) {
      a0 += lds[k * 32 + col];
      a1 += lds[TPB + k * 32 + col];
    }
    g[gi * 64 + 2 * col] = a0;
    g[gi * 64 + 2 * col + 1] = a1;
  }
}

// out[512,10] = relu(g @ Wh1 + bh1) @ Wh2 + bh2 ; thread per graph
__global__ void k_head(const float* __restrict__ g, const float* __restrict__ Wh1,
                       const float* __restrict__ bh1, const float* __restrict__ Wh2,
                       const float* __restrict__ bh2, float* __restrict__ out) {
  __shared__ float W1l[64 * 32], W2l[32 * 10], b1l[32], b2l[10];
  for (int t = threadIdx.x; t < 64 * 32; t += TPB) W1l[t] = Wh1[t];
  for (int t = threadIdx.x; t < 320; t += TPB) W2l[t] = Wh2[t];
  if (threadIdx.x < 32) b1l[threadIdx.x] = bh1[threadIdx.x];
  if (threadIdx.x < 10) b2l[threadIdx.x] = bh2[threadIdx.x];
  __syncthreads();
  int gi = blockIdx.x * TPB + threadIdx.x;
  if (gi >= NG) return;
  float hid[32];
#pragma unroll
  for (int j = 0; j < 32; ++j) hid[j] = b1l[j];
  for (int k = 0; k < 64; ++k) {
    float gv = g[gi * 64 + k];
#pragma unroll
    for (int j = 0; j < 32; ++j) hid[j] += gv * W1l[k * 32 + j];
  }
  float o[10];
#pragma unroll
  for (int j = 0; j < 10; ++j) o[j] = b2l[j];
#pragma unroll
  for (int k = 0; k < 32; ++k) {
    float hv = fmaxf(hid[k], 0.f);
#pragma unroll
    for (int j = 0; j < 10; ++j) o[j] += hv * W2l[k * 10 + j];
  }
  for (int j = 0; j < 10; ++j) out[gi * 10 + j] = o[j];
}

extern "C" void kernel_launch(void* const* d_in, const int* in_sizes, int n_in,
                              void* d_out, int out_size, void* d_ws, size_t ws_size,
                              hipStream_t stream) {
  const int* x = (const int*)d_in[0];
  const int* ei = (const int*)d_in[1];
  const int* batch = (const int*)d_in[2];
  const float* emb = (const float*)d_in[3];
  const float* W1 = (const float*)d_in[4];
  const float* b1 = (const float*)d_in[5];
  const float* g1 = (const float*)d_in[6];
  const float* bt1 = (const float*)d_in[7];
  const float* W2 = (const float*)d_in[8];
  const float* b2 = (const float*)d_in[9];
  const float* gbn = (const float*)d_in[10];
  const float* bbn = (const float*)d_in[11];
  const float* Wh1 = (const float*)d_in[12];
  const float* bh1 = (const float*)d_in[13];
  const float* Wh2 = (const float*)d_in[14];
  const float* bh2 = (const float*)d_in[15];
  float* out = (float*)d_out;

  const int* e_src = ei;
  const int* e_dst = ei + NE;

  char* ws = (char*)d_ws;
  size_t off = 0;
  auto alloc = [&](size_t bytes) -> void* {
    void* p = ws + off;
    off = (off + bytes + 255) & ~(size_t)255;
    return p;
  };
  unsigned* h_bf = (unsigned*)alloc((size_t)NN * 64 * 2);  // bf16 packed, all layers
  unsigned* zb = (unsigned*)alloc((size_t)NN * 64 * 2);    // z (bf16 packed)
  unsigned short* z2b = (unsigned short*)alloc((size_t)NN * 128 * 2);  // z2 (bf16)
  unsigned short* srcs = (unsigned short*)alloc((size_t)NE * 2);
  int* row_ptr = (int*)alloc((size_t)(NN + 1) * 4);
  int* incl = (int*)alloc((size_t)NN * 4);
  int* btot = (int*)alloc(256 * 4);
  float* g = (float*)alloc((size_t)NG * 64 * 4);
  float* partials = (float*)alloc((size_t)NBLK_G * 256 * 4);
  float* statsL = (float*)alloc(4 * 256 * 4);
  float* statsH = (float*)alloc(3 * 128 * 4);
  int* counts = (int*)alloc((size_t)NN * 4);
  int* fill_pos = (int*)alloc((size_t)NN * 4);
  int zero_words = (int)(((char*)fill_pos - (char*)counts) / 4) + NN;

  int gz = (zero_words + TPB - 1) / TPB;
  k_zero<<<gz, TPB, 0, stream>>>(counts, zero_words);

  k_hist<<<EDGE_BLKS, TPB, 0, stream>>>(e_dst, counts);

  int nScanBlocks = (NN + TPB - 1) / TPB;
  k_scan1<<<nScanBlocks, TPB, 0, stream>>>(counts, incl, btot);
  k_scan2<<<1, TPB, 0, stream>>>(btot, nScanBlocks);
  int gScan3 = (NN + 1 + TPB - 1) / TPB;
  k_scan3<<<gScan3, TPB, 0, stream>>>(incl, btot, row_ptr);
  k_fill<<<EDGE_BLKS, TPB, 0, stream>>>(e_src, e_dst, row_ptr, fill_pos, srcs);

  int gEmb = (NN * 32 + TPB - 1) / TPB;  // 6250
  k_embed_bf<<<gEmb, TPB, 0, stream>>>(x, emb, h_bf);

  int gAgg = (NN * 64 + TPB - 1) / TPB;  // 12500 (wave per node)

  for (int i = 0; i < 4; ++i) {
    const float* W1i = W1 + (size_t)i * 64 * 128;
    const float* b1i = b1 + (size_t)i * 128;
    const float* g1i = g1 + (size_t)i * 128;
    const float* bt1i = bt1 + (size_t)i * 128;
    const float* W2i = W2 + (size_t)i * 128 * 64;
    const float* b2i = b2 + (size_t)i * 64;
    float* stL = statsL + (size_t)i * 256;

    if (i == 0)
      k_aggregate_bf<false><<<gAgg, TPB, 0, stream>>>(h_bf, row_ptr, srcs, nullptr, zb);
    else
      k_aggregate_bf<true><<<gAgg, TPB, 0, stream>>>(h_bf, row_ptr, srcs,
                                                     statsH + (size_t)(i - 1) * 128, zb);

    k_gemm1<<<NBLK_G, TPB, 0, stream>>>((const unsigned short*)zb, W1i, b1i, z2b, partials);
    k_finalize<128><<<1, TPB_FIN, 0, stream>>>(partials, g1i, bt1i, stL);

    if (i < 3) {
      float* stH = statsH + (size_t)i * 128;
      k_gemm2<true><<<NBLK_G, TPB, 0, stream>>>(z2b, W2i, b2i, stL,
                                                (unsigned short*)h_bf, partials);
      k_finalize<64><<<1, TPB_FIN, 0, stream>>>(partials, gbn + (size_t)i * 64,
                                                bbn + (size_t)i * 64, stH);
    } else {
      k_gemm2<false><<<NBLK_G, TPB, 0, stream>>>(z2b, W2i, b2i, stL,
                                                 (unsigned short*)h_bf, partials);
    }
  }

  k_poolseg_bf<<<NG, TPB, 0, stream>>>(h_bf, batch, g);
  k_head<<<(NG + TPB - 1) / TPB, TPB, 0, stream>>>(g, Wh1, bh1, Wh2, bh2, out);
}

// Round 11
// 468.392 us; speedup vs baseline: 1.0786x; 1.0786x over previous
//
#include <hip/hip_runtime.h>

#define NN 50000
#define NE 800000
#define NG 512
#define TPB 256
#define BN_EPS 1e-5f
#define NBLK_G 784       // GEMM grid: ceil(NN/64)=782, padded to 784 so finalize
                         // trip count is a compile-time constant
#define EDGE_BLKS 3125   // NE/TPB exactly
#define EMB_BLKS 6250    // NN*32/TPB exactly
#define HIST_BLKS 64
#define HIST_EPB 12500   // NE/HIST_BLKS
#define HIST_WORDS 12500 // NN/4 packed u8x4 words
#define TPB_FIN 512

__device__ __forceinline__ float bf2f(unsigned u) {  // low 16 bits = bf16
  return __uint_as_float(u << 16);
}
__device__ __forceinline__ unsigned f2bf(float f) {
  unsigned u = __float_as_uint(f);
  u += 0x7FFFu + ((u >> 16) & 1u);  // round-to-nearest-even
  return u >> 16;
}

// Per-block LDS-privatized histogram: 50k bins as packed u8x4 (50KB LDS).
// Eliminates 800k global atomics (k_fill-like transaction roofline) in favor
// of LDS atomics + 3.2MB coalesced partial writes.
__global__ __launch_bounds__(TPB) void k_hist_lds(const int* __restrict__ dst,
                                                  unsigned* __restrict__ partial) {
  __shared__ unsigned hist[HIST_WORDS];
  const int t = threadIdx.x, b = blockIdx.x;
  for (int w = t; w < HIST_WORDS; w += TPB) hist[w] = 0u;
  __syncthreads();
  const int* dp = dst + b * HIST_EPB;
  for (int it = t; it < HIST_EPB; it += TPB) {
    int d = dp[it];
    atomicAdd(&hist[d >> 2], 1u << (8 * (d & 3)));
  }
  __syncthreads();
  unsigned* out = partial + (size_t)b * HIST_WORDS;
  for (int w = t; w < HIST_WORDS; w += TPB) out[w] = hist[w];
}

// Sum 64 packed partials per word (per-byte sum = node degree < 255, so plain
// u32 adds cannot carry across bytes), unpack to counts[4w..4w+3].
__global__ void k_hist_reduce(const unsigned* __restrict__ partial,
                              int* __restrict__ counts) {
  int w = blockIdx.x * TPB + threadIdx.x;
  if (w >= HIST_WORDS) return;
  unsigned s = 0;
#pragma unroll 8
  for (int b = 0; b < HIST_BLKS; ++b) s += partial[(size_t)b * HIST_WORDS + w];
  int4 o = make_int4((int)(s & 255u), (int)((s >> 8) & 255u),
                     (int)((s >> 16) & 255u), (int)(s >> 24));
  *(int4*)&counts[4 * w] = o;
}

__global__ void k_scan1(const int* __restrict__ counts, int* __restrict__ incl,
                        int* __restrict__ btot) {
  __shared__ int lds[TPB];
  int i = blockIdx.x * TPB + threadIdx.x;
  int v = (i < NN) ? counts[i] : 0;
  lds[threadIdx.x] = v;
  __syncthreads();
  for (int off = 1; off < TPB; off <<= 1) {
    int t = (threadIdx.x >= off) ? lds[threadIdx.x - off] : 0;
    __syncthreads();
    lds[threadIdx.x] += t;
    __syncthreads();
  }
  if (i < NN) incl[i] = lds[threadIdx.x];
  if (threadIdx.x == TPB - 1) btot[blockIdx.x] = lds[TPB - 1];
}

// scan2+scan3 merged: each block reduces btot[0..b) itself (196 values),
// emits row_ptr for its 256 nodes, and zeroes fill_pos (replacing k_zero).
__global__ void k_scan23(const int* __restrict__ incl, const int* __restrict__ btot,
                         int* __restrict__ row_ptr, int* __restrict__ fill_pos) {
  __shared__ int lds[TPB];
  const int t = threadIdx.x, b = blockIdx.x;
  lds[t] = (t < 196 && t < b) ? btot[t] : 0;
  __syncthreads();
  for (int off = TPB / 2; off > 0; off >>= 1) {
    if (t < off) lds[t] += lds[t + off];
    __syncthreads();
  }
  int S = lds[0];
  int i = b * TPB + t;
  if (i == 0) row_ptr[0] = 0;
  if (i < NN) {
    row_ptr[i + 1] = incl[i] + S;
    fill_pos[i] = 0;
  }
}

// Combined: blocks [0,EDGE_BLKS) run the counting-sort fill (transaction-bound
// positional atomics + ushort scatter); blocks [EDGE_BLKS,..) materialize
// h_bf[n] = bf16(emb[x[n]]) (streaming, overlaps under fill's latency).
__global__ void k_fill_embed(const int* __restrict__ src, const int* __restrict__ dst,
                             const int* __restrict__ row_ptr, int* __restrict__ fill_pos,
                             unsigned short* __restrict__ srcs,
                             const int* __restrict__ x, const float* __restrict__ emb,
                             unsigned* __restrict__ h_bf) {
  int b = blockIdx.x;
  if (b < EDGE_BLKS) {
    int e = b * TPB + threadIdx.x;
    int d = dst[e];
    int pos = row_ptr[d] + atomicAdd(&fill_pos[d], 1);
    srcs[pos] = (unsigned short)src[e];
  } else {
    int i = (b - EDGE_BLKS) * TPB + threadIdx.x;  // < NN*32 exactly
    int n = i >> 5, l = i & 31;
    float2 ev = *(const float2*)&emb[x[n] * 64 + 2 * l];
    h_bf[i] = f2bf(ev.x) | (f2bf(ev.y) << 16);
  }
}

// Aggregate over bf16 h (all 4 layers), optional BN affine of prev layer:
//   z = sc*(h_self + sum h_src) + (1+deg)*sh   -> packed bf16
// Wave per node; 32 lanes x 2 features; halves take even/odd edges,
// shfl_xor(32) combines.
template <bool BN>
__global__ void k_aggregate_bf(const unsigned* __restrict__ h_bf,
                               const int* __restrict__ row_ptr,
                               const unsigned short* __restrict__ srcs,
                               const float* __restrict__ bnst,
                               unsigned* __restrict__ zb) {
  int wid = (blockIdx.x * TPB + threadIdx.x) >> 6;
  int lane = threadIdx.x & 63;
  if (wid >= NN) return;
  int half = lane >> 5, l = lane & 31;
  int beg = row_ptr[wid], end = row_ptr[wid + 1];
  float a0 = 0.f, a1 = 0.f;
  if (half == 0) {
    unsigned u = h_bf[(size_t)wid * 32 + l];
    a0 = bf2f(u & 0xFFFF);
    a1 = bf2f(u >> 16);
  }
  int e = beg + half;
  for (; e + 6 < end; e += 8) {
    int s0 = srcs[e], s1 = srcs[e + 2], s2 = srcs[e + 4], s3 = srcs[e + 6];
    unsigned u0 = h_bf[(size_t)s0 * 32 + l];
    unsigned u1 = h_bf[(size_t)s1 * 32 + l];
    unsigned u2 = h_bf[(size_t)s2 * 32 + l];
    unsigned u3 = h_bf[(size_t)s3 * 32 + l];
    a0 += (bf2f(u0 & 0xFFFF) + bf2f(u1 & 0xFFFF)) +
          (bf2f(u2 & 0xFFFF) + bf2f(u3 & 0xFFFF));
    a1 += (bf2f(u0 >> 16) + bf2f(u1 >> 16)) + (bf2f(u2 >> 16) + bf2f(u3 >> 16));
  }
  for (; e < end; e += 2) {
    unsigned u = h_bf[(size_t)srcs[e] * 32 + l];
    a0 += bf2f(u & 0xFFFF);
    a1 += bf2f(u >> 16);
  }
  a0 += __shfl_xor(a0, 32);
  a1 += __shfl_xor(a1, 32);
  if (half == 0) {
    float zv0, zv1;
    if constexpr (BN) {
      float2 scv = *(const float2*)&bnst[2 * l];
      float2 shv = *(const float2*)&bnst[64 + 2 * l];
      float d1 = (float)(1 + end - beg);
      zv0 = fmaf(scv.x, a0, d1 * shv.x);
      zv1 = fmaf(scv.y, a1, d1 * shv.y);
    } else {
      zv0 = a0;
      zv1 = a1;
    }
    zb[(size_t)wid * 32 + l] = f2bf(zv0) | (f2bf(zv1) << 16);
  }
}

// GEMM1: z2[N,128] = z[N,64] @ W[64,128] + b1 (z bf16 in, z2 bf16 out),
// with per-block f32 column stats of z2.
__global__ __launch_bounds__(TPB) void k_gemm1(const unsigned short* __restrict__ zb,
                                               const float* __restrict__ W,
                                               const float* __restrict__ bias,
                                               unsigned short* __restrict__ z2b,
                                               float* __restrict__ partials) {
  constexpr int K = 64, NC = 128, LDA = 68;
  constexpr int TX = 32, TY = 8, RT = 8;
  __shared__ float Al[64 * LDA];
  __shared__ float Wl[K * NC];
  const int t = threadIdx.x;
  const int r0 = blockIdx.x * 64;

  {
    const float4* Wg = (const float4*)W;
    float4* Wl4 = (float4*)Wl;
#pragma unroll
    for (int j = 0; j < (K * NC / 4) / TPB; ++j) Wl4[t + j * TPB] = Wg[t + j * TPB];
  }
#pragma unroll
  for (int j = 0; j < 4; ++j) {
    int qi = t + j * TPB;
    int row = qi >> 4, cq = qi & 15;
    int r = r0 + row;
    float4 v = make_float4(0.f, 0.f, 0.f, 0.f);
    if (r < NN) {
      uint2 u = *(const uint2*)&zb[(size_t)r * 64 + cq * 4];
      v = make_float4(bf2f(u.x & 0xFFFF), bf2f(u.x >> 16), bf2f(u.y & 0xFFFF),
                      bf2f(u.y >> 16));
    }
    *(float4*)&Al[row * LDA + cq * 4] = v;
  }
  __syncthreads();

  const int tx = t % TX, ty = t / TX;
  const int c0 = tx * 4;
  float4 b0 = *(const float4*)&bias[c0];
  float acc[RT][4];
#pragma unroll
  for (int i = 0; i < RT; ++i) {
    acc[i][0] = b0.x; acc[i][1] = b0.y; acc[i][2] = b0.z; acc[i][3] = b0.w;
  }
  const float* Ab = &Al[ty * RT * LDA];
#pragma unroll 4
  for (int k4 = 0; k4 < K / 4; ++k4) {
    float4 a[RT];
#pragma unroll
    for (int i = 0; i < RT; ++i) a[i] = *(const float4*)&Ab[i * LDA + k4 * 4];
#pragma unroll
    for (int kk = 0; kk < 4; ++kk) {
      float4 b = *(const float4*)&Wl[(k4 * 4 + kk) * NC + c0];
#pragma unroll
      for (int i = 0; i < RT; ++i) {
        float av = (&a[i].x)[kk];
        acc[i][0] = fmaf(av, b.x, acc[i][0]);
        acc[i][1] = fmaf(av, b.y, acc[i][1]);
        acc[i][2] = fmaf(av, b.z, acc[i][2]);
        acc[i][3] = fmaf(av, b.w, acc[i][3]);
      }
    }
  }
  float s[4] = {0.f, 0.f, 0.f, 0.f}, q[4] = {0.f, 0.f, 0.f, 0.f};
#pragma unroll
  for (int i = 0; i < RT; ++i) {
    int r = r0 + ty * RT + i;
    if (r < NN) {
      uint2 o;
      o.x = f2bf(acc[i][0]) | (f2bf(acc[i][1]) << 16);
      o.y = f2bf(acc[i][2]) | (f2bf(acc[i][3]) << 16);
      *(uint2*)&z2b[(size_t)r * NC + c0] = o;
      s[0] += acc[i][0]; q[0] += acc[i][0] * acc[i][0];
      s[1] += acc[i][1]; q[1] += acc[i][1] * acc[i][1];
      s[2] += acc[i][2]; q[2] += acc[i][2] * acc[i][2];
      s[3] += acc[i][3]; q[3] += acc[i][3] * acc[i][3];
    }
  }
  __syncthreads();
  float* Sl = Al;  // 2*TY*NC = 2048 floats
#pragma unroll
  for (int j = 0; j < 4; ++j) {
    Sl[ty * NC + c0 + j] = s[j];
    Sl[TY * NC + ty * NC + c0 + j] = q[j];
  }
  __syncthreads();
  if (t < NC) {
    float ss = 0.f, qq = 0.f;
#pragma unroll
    for (int g = 0; g < TY; ++g) {
      ss += Sl[g * NC + t];
      qq += Sl[TY * NC + g * NC + t];
    }
    partials[blockIdx.x * 2 * NC + t] = ss;
    partials[blockIdx.x * 2 * NC + NC + t] = qq;
  }
}

// GEMM2: h[N,64] = relu( relu(bn1(z2)) @ W[128,64] + b2 ), z2 bf16 in,
// h packed bf16 out (gather/pool source).
template <bool STATS>
__global__ __launch_bounds__(TPB) void k_gemm2(const unsigned short* __restrict__ z2b,
                                               const float* __restrict__ W,
                                               const float* __restrict__ bias,
                                               const float* __restrict__ bnst,
                                               unsigned short* __restrict__ outp,
                                               float* __restrict__ partials) {
  constexpr int K = 128, NC = 64, LDA = 128;
  constexpr int TX = 16, TY = 16, RT = 4;
  __shared__ float Al[64 * LDA];
  __shared__ float Wl[K * NC];
  const int t = threadIdx.x;
  const int r0 = blockIdx.x * 64;

  {
    const float4* Wg = (const float4*)W;
    float4* Wl4 = (float4*)Wl;
#pragma unroll
    for (int j = 0; j < (K * NC / 4) / TPB; ++j) Wl4[t + j * TPB] = Wg[t + j * TPB];
  }
  {
    int cq = t & 15, rb = t >> 4;
    float4 scA = *(const float4*)&bnst[cq * 8];
    float4 scB = *(const float4*)&bnst[cq * 8 + 4];
    float4 shA = *(const float4*)&bnst[K + cq * 8];
    float4 shB = *(const float4*)&bnst[K + cq * 8 + 4];
#pragma unroll
    for (int j = 0; j < 4; ++j) {
      int row = rb + j * 16;
      int r = r0 + row;
      float4 vA = make_float4(0.f, 0.f, 0.f, 0.f), vB = vA;
      if (r < NN) {
        uint4 u = *(const uint4*)&z2b[(size_t)r * 128 + cq * 8];
        vA = make_float4(bf2f(u.x & 0xFFFF), bf2f(u.x >> 16), bf2f(u.y & 0xFFFF),
                         bf2f(u.y >> 16));
        vB = make_float4(bf2f(u.z & 0xFFFF), bf2f(u.z >> 16), bf2f(u.w & 0xFFFF),
                         bf2f(u.w >> 16));
        vA.x = fmaxf(fmaf(vA.x, scA.x, shA.x), 0.f);
        vA.y = fmaxf(fmaf(vA.y, scA.y, shA.y), 0.f);
        vA.z = fmaxf(fmaf(vA.z, scA.z, shA.z), 0.f);
        vA.w = fmaxf(fmaf(vA.w, scA.w, shA.w), 0.f);
        vB.x = fmaxf(fmaf(vB.x, scB.x, shB.x), 0.f);
        vB.y = fmaxf(fmaf(vB.y, scB.y, shB.y), 0.f);
        vB.z = fmaxf(fmaf(vB.z, scB.z, shB.z), 0.f);
        vB.w = fmaxf(fmaf(vB.w, scB.w, shB.w), 0.f);
      }
      *(float4*)&Al[row * LDA + cq * 8] = vA;
      *(float4*)&Al[row * LDA + cq * 8 + 4] = vB;
    }
  }
  __syncthreads();

  const int tx = t % TX, ty = t / TX;
  const int c0 = tx * 4;
  float4 b0 = *(const float4*)&bias[c0];
  float acc[RT][4];
#pragma unroll
  for (int i = 0; i < RT; ++i) {
    acc[i][0] = b0.x; acc[i][1] = b0.y; acc[i][2] = b0.z; acc[i][3] = b0.w;
  }
  const float* Ab = &Al[ty * RT * LDA];
#pragma unroll 4
  for (int k4 = 0; k4 < K / 4; ++k4) {
    float4 a[RT];
#pragma unroll
    for (int i = 0; i < RT; ++i) a[i] = *(const float4*)&Ab[i * LDA + k4 * 4];
#pragma unroll
    for (int kk = 0; kk < 4; ++kk) {
      float4 b = *(const float4*)&Wl[(k4 * 4 + kk) * NC + c0];
#pragma unroll
      for (int i = 0; i < RT; ++i) {
        float av = (&a[i].x)[kk];
        acc[i][0] = fmaf(av, b.x, acc[i][0]);
        acc[i][1] = fmaf(av, b.y, acc[i][1]);
        acc[i][2] = fmaf(av, b.z, acc[i][2]);
        acc[i][3] = fmaf(av, b.w, acc[i][3]);
      }
    }
  }
  float s[4] = {0.f, 0.f, 0.f, 0.f}, q[4] = {0.f, 0.f, 0.f, 0.f};
#pragma unroll
  for (int i = 0; i < RT; ++i) {
    int r = r0 + ty * RT + i;
    if (r < NN) {
      float ox = fmaxf(acc[i][0], 0.f), oy = fmaxf(acc[i][1], 0.f);
      float oz = fmaxf(acc[i][2], 0.f), ow = fmaxf(acc[i][3], 0.f);
      uint2 o;
      o.x = f2bf(ox) | (f2bf(oy) << 16);
      o.y = f2bf(oz) | (f2bf(ow) << 16);
      *(uint2*)&outp[(size_t)r * NC + c0] = o;
      if constexpr (STATS) {
        s[0] += ox; q[0] += ox * ox;
        s[1] += oy; q[1] += oy * oy;
        s[2] += oz; q[2] += oz * oz;
        s[3] += ow; q[3] += ow * ow;
      }
    }
  }
  if constexpr (STATS) {
    __syncthreads();
    float* Sl = Al;
#pragma unroll
    for (int j = 0; j < 4; ++j) {
      Sl[ty * NC + c0 + j] = s[j];
      Sl[TY * NC + ty * NC + c0 + j] = q[j];
    }
    __syncthreads();
    if (t < NC) {
      float ss = 0.f, qq = 0.f;
#pragma unroll
      for (int g = 0; g < TY; ++g) {
        ss += Sl[g * NC + t];
        qq += Sl[TY * NC + g * NC + t];
      }
      partials[blockIdx.x * 2 * NC + t] = ss;
      partials[blockIdx.x * 2 * NC + NC + t] = qq;
    }
  }
}

// Fold partials: constant trip count + unroll-8 (r8 fix), LDS tree-fold.
template <int C>
__global__ __launch_bounds__(TPB_FIN) void k_finalize(const float* __restrict__ partials,
                                                      const float* __restrict__ gamma,
                                                      const float* __restrict__ beta,
                                                      float* __restrict__ out) {
  constexpr int G = TPB_FIN / C;
  constexpr int IT = NBLK_G / G;
  __shared__ float lds[2 * TPB_FIN];
  const int c = threadIdx.x % C, g = threadIdx.x / C;
  const float* p = partials + g * 2 * C + c;
  float s = 0.f, s2 = 0.f;
#pragma unroll 8
  for (int bb = 0; bb < IT; ++bb) {
    s += p[(size_t)bb * G * 2 * C];
    s2 += p[(size_t)bb * G * 2 * C + C];
  }
  lds[threadIdx.x] = s;
  lds[TPB_FIN + threadIdx.x] = s2;
  __syncthreads();
  if (g == 0) {
#pragma unroll
    for (int k = 1; k < G; ++k) {
      s += lds[k * C + c];
      s2 += lds[TPB_FIN + k * C + c];
    }
    float invN = 1.0f / NN;
    float mu = s * invN;
    float var = s2 * invN - mu * mu;
    float rs = rsqrtf(var + BN_EPS) * gamma[c];
    out[c] = rs;
    out[C + c] = beta[c] - mu * rs;
  }
}

// Fused pool + head: block per graph; pool bf16 h rows (8 row-groups x 32
// uint cols, LDS-reduce), then compute the per-graph 2-layer MLP head
// directly (out[gi] depends only on g[gi]).
__global__ void k_poolhead(const unsigned* __restrict__ h_bf,
                           const int* __restrict__ batch,
                           const float* __restrict__ Wh1, const float* __restrict__ bh1,
                           const float* __restrict__ Wh2, const float* __restrict__ bh2,
                           float* __restrict__ out) {
  __shared__ float lds[2 * TPB];
  __shared__ float gl[64];
  __shared__ float hidl[32];
  int gi = blockIdx.x;
  int col = threadIdx.x & 31, grp = threadIdx.x >> 5;  // 8 groups
  int a = 0, b = NN;
  while (a < b) { int m = (a + b) >> 1; if (batch[m] < gi) a = m + 1; else b = m; }
  int lo = a;
  b = NN;
  while (a < b) { int m = (a + b) >> 1; if (batch[m] < gi + 1) a = m + 1; else b = m; }
  int hi = a;
  float a0 = 0.f, a1 = 0.f;
  for (int n = lo + grp; n < hi; n += 8) {
    unsigned u = h_bf[(size_t)n * 32 + col];
    a0 += bf2f(u & 0xFFFF);
    a1 += bf2f(u >> 16);
  }
  lds[threadIdx.x] = a0;
  lds[TPB + threadIdx.x] = a1;
  __syncthreads();
  if (grp == 0) {
#pragma unroll
    for (int k = 1; k < 8; ++k) {
      a0 += lds[k * 32 + col];
      a1 += lds[TPB + k * 32 + col];
    }
    gl[2 * col] = a0;
    gl[2 * col + 1] = a1;
  }
  __syncthreads();
  if (threadIdx.x < 32) {
    int j = threadIdx.x;
    float hid = bh1[j];
    for (int k = 0; k < 64; ++k) hid = fmaf(gl[k], Wh1[k * 32 + j], hid);
    hidl[j] = fmaxf(hid, 0.f);
  }
  __syncthreads();
  if (threadIdx.x < 10) {
    int j = threadIdx.x;
    float o = bh2[j];
#pragma unroll
    for (int k = 0; k < 32; ++k) o = fmaf(hidl[k], Wh2[k * 10 + j], o);
    out[gi * 10 + j] = o;
  }
}

extern "C" void kernel_launch(void* const* d_in, const int* in_sizes, int n_in,
                              void* d_out, int out_size, void* d_ws, size_t ws_size,
                              hipStream_t stream) {
  const int* x = (const int*)d_in[0];
  const int* ei = (const int*)d_in[1];
  const int* batch = (const int*)d_in[2];
  const float* emb = (const float*)d_in[3];
  const float* W1 = (const float*)d_in[4];
  const float* b1 = (const float*)d_in[5];
  const float* g1 = (const float*)d_in[6];
  const float* bt1 = (const float*)d_in[7];
  const float* W2 = (const float*)d_in[8];
  const float* b2 = (const float*)d_in[9];
  const float* gbn = (const float*)d_in[10];
  const float* bbn = (const float*)d_in[11];
  const float* Wh1 = (const float*)d_in[12];
  const float* bh1 = (const float*)d_in[13];
  const float* Wh2 = (const float*)d_in[14];
  const float* bh2 = (const float*)d_in[15];
  float* out = (float*)d_out;

  const int* e_src = ei;
  const int* e_dst = ei + NE;

  char* ws = (char*)d_ws;
  size_t off = 0;
  auto alloc = [&](size_t bytes) -> void* {
    void* p = ws + off;
    off = (off + bytes + 255) & ~(size_t)255;
    return p;
  };
  unsigned* h_bf = (unsigned*)alloc((size_t)NN * 64 * 2);  // bf16 packed, all layers
  unsigned* zb = (unsigned*)alloc((size_t)NN * 64 * 2);    // z (bf16 packed)
  unsigned short* z2b = (unsigned short*)alloc((size_t)NN * 128 * 2);  // z2 (bf16)
  unsigned short* srcs = (unsigned short*)alloc((size_t)NE * 2);
  int* row_ptr = (int*)alloc((size_t)(NN + 1) * 4);
  int* incl = (int*)alloc((size_t)NN * 4);
  int* btot = (int*)alloc(256 * 4);
  float* partials = (float*)alloc((size_t)NBLK_G * 256 * 4);
  float* statsL = (float*)alloc(4 * 256 * 4);
  float* statsH = (float*)alloc(3 * 128 * 4);
  int* counts = (int*)alloc((size_t)NN * 4);
  int* fill_pos = (int*)alloc((size_t)NN * 4);
  unsigned* histpart = (unsigned*)alloc((size_t)HIST_BLKS * HIST_WORDS * 4);

  k_hist_lds<<<HIST_BLKS, TPB, 0, stream>>>(e_dst, histpart);
  k_hist_reduce<<<(HIST_WORDS + TPB - 1) / TPB, TPB, 0, stream>>>(histpart, counts);

  int nScanBlocks = (NN + TPB - 1) / TPB;  // 196
  k_scan1<<<nScanBlocks, TPB, 0, stream>>>(counts, incl, btot);
  k_scan23<<<nScanBlocks, TPB, 0, stream>>>(incl, btot, row_ptr, fill_pos);
  k_fill_embed<<<EDGE_BLKS + EMB_BLKS, TPB, 0, stream>>>(e_src, e_dst, row_ptr, fill_pos,
                                                         srcs, x, emb, h_bf);

  int gAgg = (NN * 64 + TPB - 1) / TPB;  // 12500 (wave per node)

  for (int i = 0; i < 4; ++i) {
    const float* W1i = W1 + (size_t)i * 64 * 128;
    const float* b1i = b1 + (size_t)i * 128;
    const float* g1i = g1 + (size_t)i * 128;
    const float* bt1i = bt1 + (size_t)i * 128;
    const float* W2i = W2 + (size_t)i * 128 * 64;
    const float* b2i = b2 + (size_t)i * 64;
    float* stL = statsL + (size_t)i * 256;

    if (i == 0)
      k_aggregate_bf<false><<<gAgg, TPB, 0, stream>>>(h_bf, row_ptr, srcs, nullptr, zb);
    else
      k_aggregate_bf<true><<<gAgg, TPB, 0, stream>>>(h_bf, row_ptr, srcs,
                                                     statsH + (size_t)(i - 1) * 128, zb);

    k_gemm1<<<NBLK_G, TPB, 0, stream>>>((const unsigned short*)zb, W1i, b1i, z2b, partials);
    k_finalize<128><<<1, TPB_FIN, 0, stream>>>(partials, g1i, bt1i, stL);

    if (i < 3) {
      float* stH = statsH + (size_t)i * 128;
      k_gemm2<true><<<NBLK_G, TPB, 0, stream>>>(z2b, W2i, b2i, stL,
                                                (unsigned short*)h_bf, partials);
      k_finalize<64><<<1, TPB_FIN, 0, stream>>>(partials, gbn + (size_t)i * 64,
                                                bbn + (size_t)i * 64, stH);
    } else {
      k_gemm2<false><<<NBLK_G, TPB, 0, stream>>>(z2b, W2i, b2i, stL,
                                                 (unsigned short*)h_bf, partials);
    }
  }

  k_poolhead<<<NG, TPB, 0, stream>>>(h_bf, batch, Wh1, bh1, Wh2, bh2, out);
}

// Round 12
// 450.943 us; speedup vs baseline: 1.1203x; 1.0387x over previous
//
#include <hip/hip_runtime.h>

#define NN 50000
#define NE 800000
#define NG 512
#define TPB 256
#define BN_EPS 1e-5f
#define NBLK_G 784       // GEMM grid: ceil(NN/64)=782, padded to 784 so finalize
                         // trip count is a compile-time constant
#define EMB_BLKS 6250    // NN*32/TPB exactly
#define HIST_BLKS 64
#define HIST_EPB 12500   // NE/HIST_BLKS
#define HIST_WORDS 12500 // NN/4 packed u8x4 words
#define TPB_FIN 512

__device__ __forceinline__ float bf2f(unsigned u) {  // low 16 bits = bf16
  return __uint_as_float(u << 16);
}
__device__ __forceinline__ unsigned f2bf(float f) {
  unsigned u = __float_as_uint(f);
  u += 0x7FFFu + ((u >> 16) & 1u);  // round-to-nearest-even
  return u >> 16;
}

// Pass 1: per-block LDS-privatized histogram (50k bins packed u8x4, 50KB LDS)
// AND per-edge within-block rank (LDS atomicAdd returns the old count).
// No global atomics anywhere.
__global__ __launch_bounds__(TPB) void k_hist_lds(const int* __restrict__ dst,
                                                  unsigned* __restrict__ partial,
                                                  unsigned char* __restrict__ rank8) {
  __shared__ unsigned hist[HIST_WORDS];
  const int t = threadIdx.x, b = blockIdx.x;
  for (int w = t; w < HIST_WORDS; w += TPB) hist[w] = 0u;
  __syncthreads();
  const int* dp = dst + b * HIST_EPB;
  unsigned char* rp = rank8 + b * HIST_EPB;
  for (int it = t; it < HIST_EPB; it += TPB) {
    int d = dp[it];
    unsigned sh = 8u * (d & 3);
    unsigned old = atomicAdd(&hist[d >> 2], 1u << sh);
    rp[it] = (unsigned char)((old >> sh) & 255u);
  }
  __syncthreads();
  unsigned* out = partial + (size_t)b * HIST_WORDS;
  for (int w = t; w < HIST_WORDS; w += TPB) out[w] = hist[w];
}

// Pass 2: per node-word, exclusive prefix over the 64 block histograms IN
// PLACE (packed u8 lanes; per-node degree < 255 so no cross-byte carries),
// and emit total counts.
__global__ void k_hist_scan(unsigned* __restrict__ partial, int* __restrict__ counts) {
  int w = blockIdx.x * TPB + threadIdx.x;
  if (w >= HIST_WORDS) return;
  unsigned run = 0;
#pragma unroll 8
  for (int b = 0; b < HIST_BLKS; ++b) {
    unsigned v = partial[(size_t)b * HIST_WORDS + w];
    partial[(size_t)b * HIST_WORDS + w] = run;
    run += v;
  }
  *(int4*)&counts[4 * w] = make_int4((int)(run & 255u), (int)((run >> 8) & 255u),
                                     (int)((run >> 16) & 255u), (int)(run >> 24));
}

__global__ void k_scan1(const int* __restrict__ counts, int* __restrict__ incl,
                        int* __restrict__ btot) {
  __shared__ int lds[TPB];
  int i = blockIdx.x * TPB + threadIdx.x;
  int v = (i < NN) ? counts[i] : 0;
  lds[threadIdx.x] = v;
  __syncthreads();
  for (int off = 1; off < TPB; off <<= 1) {
    int t = (threadIdx.x >= off) ? lds[threadIdx.x - off] : 0;
    __syncthreads();
    lds[threadIdx.x] += t;
    __syncthreads();
  }
  if (i < NN) incl[i] = lds[threadIdx.x];
  if (threadIdx.x == TPB - 1) btot[blockIdx.x] = lds[TPB - 1];
}

// scan2+scan3 merged: each block reduces btot[0..b) itself, emits row_ptr.
__global__ void k_scan23(const int* __restrict__ incl, const int* __restrict__ btot,
                         int* __restrict__ row_ptr) {
  __shared__ int lds[TPB];
  const int t = threadIdx.x, b = blockIdx.x;
  lds[t] = (t < 196 && t < b) ? btot[t] : 0;
  __syncthreads();
  for (int off = TPB / 2; off > 0; off >>= 1) {
    if (t < off) lds[t] += lds[t + off];
    __syncthreads();
  }
  int S = lds[0];
  int i = b * TPB + t;
  if (i == 0) row_ptr[0] = 0;
  if (i < NN) row_ptr[i + 1] = incl[i] + S;
}

// Atomic-free fill + embed. Blocks [0,HIST_BLKS): load this block's exclusive
// prefix into LDS, then pos = row_ptr[d] + prefix[b][d] + rank8[e] — pure
// reads + ushort scatter (the 800k global atomic RMWs that dominated r11's
// 52MB WRITE_SIZE are gone). Blocks [HIST_BLKS,..): h_bf[n] = bf16(emb[x[n]]).
__global__ __launch_bounds__(TPB) void k_fill_embed(
    const int* __restrict__ src, const int* __restrict__ dst,
    const unsigned* __restrict__ partial, const unsigned char* __restrict__ rank8,
    const int* __restrict__ row_ptr, unsigned short* __restrict__ srcs,
    const int* __restrict__ x, const float* __restrict__ emb,
    unsigned* __restrict__ h_bf) {
  __shared__ unsigned pref[HIST_WORDS];
  int b = blockIdx.x;
  if (b < HIST_BLKS) {
    const unsigned* pp = partial + (size_t)b * HIST_WORDS;
    for (int w = threadIdx.x; w < HIST_WORDS; w += TPB) pref[w] = pp[w];
    __syncthreads();
    const int* dp = dst + b * HIST_EPB;
    const int* sp = src + b * HIST_EPB;
    const unsigned char* rp = rank8 + b * HIST_EPB;
    for (int it = threadIdx.x; it < HIST_EPB; it += TPB) {
      int d = dp[it];
      unsigned base = (pref[d >> 2] >> (8u * (d & 3))) & 255u;
      int pos = row_ptr[d] + (int)base + (int)rp[it];
      srcs[pos] = (unsigned short)sp[it];
    }
  } else {
    int i = (b - HIST_BLKS) * TPB + threadIdx.x;  // < NN*32 exactly
    int n = i >> 5, l = i & 31;
    float2 ev = *(const float2*)&emb[x[n] * 64 + 2 * l];
    h_bf[i] = f2bf(ev.x) | (f2bf(ev.y) << 16);
  }
}

// Aggregate over bf16 h (all 4 layers), optional BN affine of prev layer:
//   z = sc*(h_self + sum h_src) + (1+deg)*sh   -> packed bf16
template <bool BN>
__global__ void k_aggregate_bf(const unsigned* __restrict__ h_bf,
                               const int* __restrict__ row_ptr,
                               const unsigned short* __restrict__ srcs,
                               const float* __restrict__ bnst,
                               unsigned* __restrict__ zb) {
  int wid = (blockIdx.x * TPB + threadIdx.x) >> 6;
  int lane = threadIdx.x & 63;
  if (wid >= NN) return;
  int half = lane >> 5, l = lane & 31;
  int beg = row_ptr[wid], end = row_ptr[wid + 1];
  float a0 = 0.f, a1 = 0.f;
  if (half == 0) {
    unsigned u = h_bf[(size_t)wid * 32 + l];
    a0 = bf2f(u & 0xFFFF);
    a1 = bf2f(u >> 16);
  }
  int e = beg + half;
  for (; e + 6 < end; e += 8) {
    int s0 = srcs[e], s1 = srcs[e + 2], s2 = srcs[e + 4], s3 = srcs[e + 6];
    unsigned u0 = h_bf[(size_t)s0 * 32 + l];
    unsigned u1 = h_bf[(size_t)s1 * 32 + l];
    unsigned u2 = h_bf[(size_t)s2 * 32 + l];
    unsigned u3 = h_bf[(size_t)s3 * 32 + l];
    a0 += (bf2f(u0 & 0xFFFF) + bf2f(u1 & 0xFFFF)) +
          (bf2f(u2 & 0xFFFF) + bf2f(u3 & 0xFFFF));
    a1 += (bf2f(u0 >> 16) + bf2f(u1 >> 16)) + (bf2f(u2 >> 16) + bf2f(u3 >> 16));
  }
  for (; e < end; e += 2) {
    unsigned u = h_bf[(size_t)srcs[e] * 32 + l];
    a0 += bf2f(u & 0xFFFF);
    a1 += bf2f(u >> 16);
  }
  a0 += __shfl_xor(a0, 32);
  a1 += __shfl_xor(a1, 32);
  if (half == 0) {
    float zv0, zv1;
    if constexpr (BN) {
      float2 scv = *(const float2*)&bnst[2 * l];
      float2 shv = *(const float2*)&bnst[64 + 2 * l];
      float d1 = (float)(1 + end - beg);
      zv0 = fmaf(scv.x, a0, d1 * shv.x);
      zv1 = fmaf(scv.y, a1, d1 * shv.y);
    } else {
      zv0 = a0;
      zv1 = a1;
    }
    zb[(size_t)wid * 32 + l] = f2bf(zv0) | (f2bf(zv1) << 16);
  }
}

// GEMM1: z2[N,128] = z[N,64] @ W[64,128] + b1 (z bf16 in, z2 bf16 out),
// with per-block f32 column stats of z2.
__global__ __launch_bounds__(TPB) void k_gemm1(const unsigned short* __restrict__ zb,
                                               const float* __restrict__ W,
                                               const float* __restrict__ bias,
                                               unsigned short* __restrict__ z2b,
                                               float* __restrict__ partials) {
  constexpr int K = 64, NC = 128, LDA = 68;
  constexpr int TX = 32, TY = 8, RT = 8;
  __shared__ float Al[64 * LDA];
  __shared__ float Wl[K * NC];
  const int t = threadIdx.x;
  const int r0 = blockIdx.x * 64;

  {
    const float4* Wg = (const float4*)W;
    float4* Wl4 = (float4*)Wl;
#pragma unroll
    for (int j = 0; j < (K * NC / 4) / TPB; ++j) Wl4[t + j * TPB] = Wg[t + j * TPB];
  }
#pragma unroll
  for (int j = 0; j < 4; ++j) {
    int qi = t + j * TPB;
    int row = qi >> 4, cq = qi & 15;
    int r = r0 + row;
    float4 v = make_float4(0.f, 0.f, 0.f, 0.f);
    if (r < NN) {
      uint2 u = *(const uint2*)&zb[(size_t)r * 64 + cq * 4];
      v = make_float4(bf2f(u.x & 0xFFFF), bf2f(u.x >> 16), bf2f(u.y & 0xFFFF),
                      bf2f(u.y >> 16));
    }
    *(float4*)&Al[row * LDA + cq * 4] = v;
  }
  __syncthreads();

  const int tx = t % TX, ty = t / TX;
  const int c0 = tx * 4;
  float4 b0 = *(const float4*)&bias[c0];
  float acc[RT][4];
#pragma unroll
  for (int i = 0; i < RT; ++i) {
    acc[i][0] = b0.x; acc[i][1] = b0.y; acc[i][2] = b0.z; acc[i][3] = b0.w;
  }
  const float* Ab = &Al[ty * RT * LDA];
#pragma unroll 4
  for (int k4 = 0; k4 < K / 4; ++k4) {
    float4 a[RT];
#pragma unroll
    for (int i = 0; i < RT; ++i) a[i] = *(const float4*)&Ab[i * LDA + k4 * 4];
#pragma unroll
    for (int kk = 0; kk < 4; ++kk) {
      float4 b = *(const float4*)&Wl[(k4 * 4 + kk) * NC + c0];
#pragma unroll
      for (int i = 0; i < RT; ++i) {
        float av = (&a[i].x)[kk];
        acc[i][0] = fmaf(av, b.x, acc[i][0]);
        acc[i][1] = fmaf(av, b.y, acc[i][1]);
        acc[i][2] = fmaf(av, b.z, acc[i][2]);
        acc[i][3] = fmaf(av, b.w, acc[i][3]);
      }
    }
  }
  float s[4] = {0.f, 0.f, 0.f, 0.f}, q[4] = {0.f, 0.f, 0.f, 0.f};
#pragma unroll
  for (int i = 0; i < RT; ++i) {
    int r = r0 + ty * RT + i;
    if (r < NN) {
      uint2 o;
      o.x = f2bf(acc[i][0]) | (f2bf(acc[i][1]) << 16);
      o.y = f2bf(acc[i][2]) | (f2bf(acc[i][3]) << 16);
      *(uint2*)&z2b[(size_t)r * NC + c0] = o;
      s[0] += acc[i][0]; q[0] += acc[i][0] * acc[i][0];
      s[1] += acc[i][1]; q[1] += acc[i][1] * acc[i][1];
      s[2] += acc[i][2]; q[2] += acc[i][2] * acc[i][2];
      s[3] += acc[i][3]; q[3] += acc[i][3] * acc[i][3];
    }
  }
  __syncthreads();
  float* Sl = Al;  // 2*TY*NC = 2048 floats
#pragma unroll
  for (int j = 0; j < 4; ++j) {
    Sl[ty * NC + c0 + j] = s[j];
    Sl[TY * NC + ty * NC + c0 + j] = q[j];
  }
  __syncthreads();
  if (t < NC) {
    float ss = 0.f, qq = 0.f;
#pragma unroll
    for (int g = 0; g < TY; ++g) {
      ss += Sl[g * NC + t];
      qq += Sl[TY * NC + g * NC + t];
    }
    partials[blockIdx.x * 2 * NC + t] = ss;
    partials[blockIdx.x * 2 * NC + NC + t] = qq;
  }
}

// GEMM2: h[N,64] = relu( relu(bn1(z2)) @ W[128,64] + b2 ), z2 bf16 in,
// h packed bf16 out (gather/pool source).
template <bool STATS>
__global__ __launch_bounds__(TPB) void k_gemm2(const unsigned short* __restrict__ z2b,
                                               const float* __restrict__ W,
                                               const float* __restrict__ bias,
                                               const float* __restrict__ bnst,
                                               unsigned short* __restrict__ outp,
                                               float* __restrict__ partials) {
  constexpr int K = 128, NC = 64, LDA = 128;
  constexpr int TX = 16, TY = 16, RT = 4;
  __shared__ float Al[64 * LDA];
  __shared__ float Wl[K * NC];
  const int t = threadIdx.x;
  const int r0 = blockIdx.x * 64;

  {
    const float4* Wg = (const float4*)W;
    float4* Wl4 = (float4*)Wl;
#pragma unroll
    for (int j = 0; j < (K * NC / 4) / TPB; ++j) Wl4[t + j * TPB] = Wg[t + j * TPB];
  }
  {
    int cq = t & 15, rb = t >> 4;
    float4 scA = *(const float4*)&bnst[cq * 8];
    float4 scB = *(const float4*)&bnst[cq * 8 + 4];
    float4 shA = *(const float4*)&bnst[K + cq * 8];
    float4 shB = *(const float4*)&bnst[K + cq * 8 + 4];
#pragma unroll
    for (int j = 0; j < 4; ++j) {
      int row = rb + j * 16;
      int r = r0 + row;
      float4 vA = make_float4(0.f, 0.f, 0.f, 0.f), vB = vA;
      if (r < NN) {
        uint4 u = *(const uint4*)&z2b[(size_t)r * 128 + cq * 8];
        vA = make_float4(bf2f(u.x & 0xFFFF), bf2f(u.x >> 16), bf2f(u.y & 0xFFFF),
                         bf2f(u.y >> 16));
        vB = make_float4(bf2f(u.z & 0xFFFF), bf2f(u.z >> 16), bf2f(u.w & 0xFFFF),
                         bf2f(u.w >> 16));
        vA.x = fmaxf(fmaf(vA.x, scA.x, shA.x), 0.f);
        vA.y = fmaxf(fmaf(vA.y, scA.y, shA.y), 0.f);
        vA.z = fmaxf(fmaf(vA.z, scA.z, shA.z), 0.f);
        vA.w = fmaxf(fmaf(vA.w, scA.w, shA.w), 0.f);
        vB.x = fmaxf(fmaf(vB.x, scB.x, shB.x), 0.f);
        vB.y = fmaxf(fmaf(vB.y, scB.y, shB.y), 0.f);
        vB.z = fmaxf(fmaf(vB.z, scB.z, shB.z), 0.f);
        vB.w = fmaxf(fmaf(vB.w, scB.w, shB.w), 0.f);
      }
      *(float4*)&Al[row * LDA + cq * 8] = vA;
      *(float4*)&Al[row * LDA + cq * 8 + 4] = vB;
    }
  }
  __syncthreads();

  const int tx = t % TX, ty = t / TX;
  const int c0 = tx * 4;
  float4 b0 = *(const float4*)&bias[c0];
  float acc[RT][4];
#pragma unroll
  for (int i = 0; i < RT; ++i) {
    acc[i][0] = b0.x; acc[i][1] = b0.y; acc[i][2] = b0.z; acc[i][3] = b0.w;
  }
  const float* Ab = &Al[ty * RT * LDA];
#pragma unroll 4
  for (int k4 = 0; k4 < K / 4; ++k4) {
    float4 a[RT];
#pragma unroll
    for (int i = 0; i < RT; ++i) a[i] = *(const float4*)&Ab[i * LDA + k4 * 4];
#pragma unroll
    for (int kk = 0; kk < 4; ++kk) {
      float4 b = *(const float4*)&Wl[(k4 * 4 + kk) * NC + c0];
#pragma unroll
      for (int i = 0; i < RT; ++i) {
        float av = (&a[i].x)[kk];
        acc[i][0] = fmaf(av, b.x, acc[i][0]);
        acc[i][1] = fmaf(av, b.y, acc[i][1]);
        acc[i][2] = fmaf(av, b.z, acc[i][2]);
        acc[i][3] = fmaf(av, b.w, acc[i][3]);
      }
    }
  }
  float s[4] = {0.f, 0.f, 0.f, 0.f}, q[4] = {0.f, 0.f, 0.f, 0.f};
#pragma unroll
  for (int i = 0; i < RT; ++i) {
    int r = r0 + ty * RT + i;
    if (r < NN) {
      float ox = fmaxf(acc[i][0], 0.f), oy = fmaxf(acc[i][1], 0.f);
      float oz = fmaxf(acc[i][2], 0.f), ow = fmaxf(acc[i][3], 0.f);
      uint2 o;
      o.x = f2bf(ox) | (f2bf(oy) << 16);
      o.y = f2bf(oz) | (f2bf(ow) << 16);
      *(uint2*)&outp[(size_t)r * NC + c0] = o;
      if constexpr (STATS) {
        s[0] += ox; q[0] += ox * ox;
        s[1] += oy; q[1] += oy * oy;
        s[2] += oz; q[2] += oz * oz;
        s[3] += ow; q[3] += ow * ow;
      }
    }
  }
  if constexpr (STATS) {
    __syncthreads();
    float* Sl = Al;
#pragma unroll
    for (int j = 0; j < 4; ++j) {
      Sl[ty * NC + c0 + j] = s[j];
      Sl[TY * NC + ty * NC + c0 + j] = q[j];
    }
    __syncthreads();
    if (t < NC) {
      float ss = 0.f, qq = 0.f;
#pragma unroll
      for (int g = 0; g < TY; ++g) {
        ss += Sl[g * NC + t];
        qq += Sl[TY * NC + g * NC + t];
      }
      partials[blockIdx.x * 2 * NC + t] = ss;
      partials[blockIdx.x * 2 * NC + NC + t] = qq;
    }
  }
}

// Fold partials: constant trip count + unroll-8 (r8 fix), LDS tree-fold.
template <int C>
__global__ __launch_bounds__(TPB_FIN) void k_finalize(const float* __restrict__ partials,
                                                      const float* __restrict__ gamma,
                                                      const float* __restrict__ beta,
                                                      float* __restrict__ out) {
  constexpr int G = TPB_FIN / C;
  constexpr int IT = NBLK_G / G;
  __shared__ float lds[2 * TPB_FIN];
  const int c = threadIdx.x % C, g = threadIdx.x / C;
  const float* p = partials + g * 2 * C + c;
  float s = 0.f, s2 = 0.f;
#pragma unroll 8
  for (int bb = 0; bb < IT; ++bb) {
    s += p[(size_t)bb * G * 2 * C];
    s2 += p[(size_t)bb * G * 2 * C + C];
  }
  lds[threadIdx.x] = s;
  lds[TPB_FIN + threadIdx.x] = s2;
  __syncthreads();
  if (g == 0) {
#pragma unroll
    for (int k = 1; k < G; ++k) {
      s += lds[k * C + c];
      s2 += lds[TPB_FIN + k * C + c];
    }
    float invN = 1.0f / NN;
    float mu = s * invN;
    float var = s2 * invN - mu * mu;
    float rs = rsqrtf(var + BN_EPS) * gamma[c];
    out[c] = rs;
    out[C + c] = beta[c] - mu * rs;
  }
}

// Fused pool + head: block per graph.
__global__ void k_poolhead(const unsigned* __restrict__ h_bf,
                           const int* __restrict__ batch,
                           const float* __restrict__ Wh1, const float* __restrict__ bh1,
                           const float* __restrict__ Wh2, const float* __restrict__ bh2,
                           float* __restrict__ out) {
  __shared__ float lds[2 * TPB];
  __shared__ float gl[64];
  __shared__ float hidl[32];
  int gi = blockIdx.x;
  int col = threadIdx.x & 31, grp = threadIdx.x >> 5;  // 8 groups
  int a = 0, b = NN;
  while (a < b) { int m = (a + b) >> 1; if (batch[m] < gi) a = m + 1; else b = m; }
  int lo = a;
  b = NN;
  while (a < b) { int m = (a + b) >> 1; if (batch[m] < gi + 1) a = m + 1; else b = m; }
  int hi = a;
  float a0 = 0.f, a1 = 0.f;
  for (int n = lo + grp; n < hi; n += 8) {
    unsigned u = h_bf[(size_t)n * 32 + col];
    a0 += bf2f(u & 0xFFFF);
    a1 += bf2f(u >> 16);
  }
  lds[threadIdx.x] = a0;
  lds[TPB + threadIdx.x] = a1;
  __syncthreads();
  if (grp == 0) {
#pragma unroll
    for (int k = 1; k < 8; ++k) {
      a0 += lds[k * 32 + col];
      a1 += lds[TPB + k * 32 + col];
    }
    gl[2 * col] = a0;
    gl[2 * col + 1] = a1;
  }
  __syncthreads();
  if (threadIdx.x < 32) {
    int j = threadIdx.x;
    float hid = bh1[j];
    for (int k = 0; k < 64; ++k) hid = fmaf(gl[k], Wh1[k * 32 + j], hid);
    hidl[j] = fmaxf(hid, 0.f);
  }
  __syncthreads();
  if (threadIdx.x < 10) {
    int j = threadIdx.x;
    float o = bh2[j];
#pragma unroll
    for (int k = 0; k < 32; ++k) o = fmaf(hidl[k], Wh2[k * 10 + j], o);
    out[gi * 10 + j] = o;
  }
}

extern "C" void kernel_launch(void* const* d_in, const int* in_sizes, int n_in,
                              void* d_out, int out_size, void* d_ws, size_t ws_size,
                              hipStream_t stream) {
  const int* x = (const int*)d_in[0];
  const int* ei = (const int*)d_in[1];
  const int* batch = (const int*)d_in[2];
  const float* emb = (const float*)d_in[3];
  const float* W1 = (const float*)d_in[4];
  const float* b1 = (const float*)d_in[5];
  const float* g1 = (const float*)d_in[6];
  const float* bt1 = (const float*)d_in[7];
  const float* W2 = (const float*)d_in[8];
  const float* b2 = (const float*)d_in[9];
  const float* gbn = (const float*)d_in[10];
  const float* bbn = (const float*)d_in[11];
  const float* Wh1 = (const float*)d_in[12];
  const float* bh1 = (const float*)d_in[13];
  const float* Wh2 = (const float*)d_in[14];
  const float* bh2 = (const float*)d_in[15];
  float* out = (float*)d_out;

  const int* e_src = ei;
  const int* e_dst = ei + NE;

  char* ws = (char*)d_ws;
  size_t off = 0;
  auto alloc = [&](size_t bytes) -> void* {
    void* p = ws + off;
    off = (off + bytes + 255) & ~(size_t)255;
    return p;
  };
  unsigned* h_bf = (unsigned*)alloc((size_t)NN * 64 * 2);  // bf16 packed, all layers
  unsigned* zb = (unsigned*)alloc((size_t)NN * 64 * 2);    // z (bf16 packed)
  unsigned short* z2b = (unsigned short*)alloc((size_t)NN * 128 * 2);  // z2 (bf16)
  unsigned short* srcs = (unsigned short*)alloc((size_t)NE * 2);
  unsigned char* rank8 = (unsigned char*)alloc((size_t)NE);
  int* row_ptr = (int*)alloc((size_t)(NN + 1) * 4);
  int* incl = (int*)alloc((size_t)NN * 4);
  int* btot = (int*)alloc(256 * 4);
  float* partials = (float*)alloc((size_t)NBLK_G * 256 * 4);
  float* statsL = (float*)alloc(4 * 256 * 4);
  float* statsH = (float*)alloc(3 * 128 * 4);
  int* counts = (int*)alloc((size_t)NN * 4);
  unsigned* histpart = (unsigned*)alloc((size_t)HIST_BLKS * HIST_WORDS * 4);

  k_hist_lds<<<HIST_BLKS, TPB, 0, stream>>>(e_dst, histpart, rank8);
  k_hist_scan<<<(HIST_WORDS + TPB - 1) / TPB, TPB, 0, stream>>>(histpart, counts);

  int nScanBlocks = (NN + TPB - 1) / TPB;  // 196
  k_scan1<<<nScanBlocks, TPB, 0, stream>>>(counts, incl, btot);
  k_scan23<<<nScanBlocks, TPB, 0, stream>>>(incl, btot, row_ptr);
  k_fill_embed<<<HIST_BLKS + EMB_BLKS, TPB, 0, stream>>>(e_src, e_dst, histpart, rank8,
                                                         row_ptr, srcs, x, emb, h_bf);

  int gAgg = (NN * 64 + TPB - 1) / TPB;  // 12500 (wave per node)

  for (int i = 0; i < 4; ++i) {
    const float* W1i = W1 + (size_t)i * 64 * 128;
    const float* b1i = b1 + (size_t)i * 128;
    const float* g1i = g1 + (size_t)i * 128;
    const float* bt1i = bt1 + (size_t)i * 128;
    const float* W2i = W2 + (size_t)i * 128 * 64;
    const float* b2i = b2 + (size_t)i * 64;
    float* stL = statsL + (size_t)i * 256;

    if (i == 0)
      k_aggregate_bf<false><<<gAgg, TPB, 0, stream>>>(h_bf, row_ptr, srcs, nullptr, zb);
    else
      k_aggregate_bf<true><<<gAgg, TPB, 0, stream>>>(h_bf, row_ptr, srcs,
                                                     statsH + (size_t)(i - 1) * 128, zb);

    k_gemm1<<<NBLK_G, TPB, 0, stream>>>((const unsigned short*)zb, W1i, b1i, z2b, partials);
    k_finalize<128><<<1, TPB_FIN, 0, stream>>>(partials, g1i, bt1i, stL);

    if (i < 3) {
      float* stH = statsH + (size_t)i * 128;
      k_gemm2<true><<<NBLK_G, TPB, 0, stream>>>(z2b, W2i, b2i, stL,
                                                (unsigned short*)h_bf, partials);
      k_finalize<64><<<1, TPB_FIN, 0, stream>>>(partials, gbn + (size_t)i * 64,
                                                bbn + (size_t)i * 64, stH);
    } else {
      k_gemm2<false><<<NBLK_G, TPB, 0, stream>>>(z2b, W2i, b2i, stL,
                                                 (unsigned short*)h_bf, partials);
    }
  }

  k_poolhead<<<NG, TPB, 0, stream>>>(h_bf, batch, Wh1, bh1, Wh2, bh2, out);
}

// Round 13
// 380.155 us; speedup vs baseline: 1.3289x; 1.1862x over previous
//
#include <hip/hip_runtime.h>

#define NN 50000
#define NE 800000
#define NG 512
#define TPB 256
#define BN_EPS 1e-5f
#define NBLK_G 784       // GEMM grid: ceil(NN/64)=782, padded to 784 so finalize
                         // trip count is a compile-time constant
#define EMB_BLKS 6250    // NN*32/TPB exactly
#define HIST_BLKS 64
#define HIST_EPB 12500   // NE/HIST_BLKS
#define HIST_WORDS 12500 // NN/4 packed u8x4 words
#define TPB_FIN 512

typedef __attribute__((ext_vector_type(8))) short bf16x8;
typedef __attribute__((ext_vector_type(4))) float f32x4;

__device__ __forceinline__ float bf2f(unsigned u) {  // low 16 bits = bf16
  return __uint_as_float(u << 16);
}
__device__ __forceinline__ unsigned f2bf(float f) {
  unsigned u = __float_as_uint(f);
  u += 0x7FFFu + ((u >> 16) & 1u);  // round-to-nearest-even
  return u >> 16;
}

// Pass 1: per-block LDS-privatized histogram + per-edge within-block rank.
__global__ __launch_bounds__(TPB) void k_hist_lds(const int* __restrict__ dst,
                                                  unsigned* __restrict__ partial,
                                                  unsigned char* __restrict__ rank8) {
  __shared__ unsigned hist[HIST_WORDS];
  const int t = threadIdx.x, b = blockIdx.x;
  for (int w = t; w < HIST_WORDS; w += TPB) hist[w] = 0u;
  __syncthreads();
  const int* dp = dst + b * HIST_EPB;
  unsigned char* rp = rank8 + b * HIST_EPB;
  for (int it = t; it < HIST_EPB; it += TPB) {
    int d = dp[it];
    unsigned sh = 8u * (d & 3);
    unsigned old = atomicAdd(&hist[d >> 2], 1u << sh);
    rp[it] = (unsigned char)((old >> sh) & 255u);
  }
  __syncthreads();
  unsigned* out = partial + (size_t)b * HIST_WORDS;
  for (int w = t; w < HIST_WORDS; w += TPB) out[w] = hist[w];
}

// Pass 2: exclusive prefix over the 64 block histograms in place; emit counts.
__global__ void k_hist_scan(unsigned* __restrict__ partial, int* __restrict__ counts) {
  int w = blockIdx.x * TPB + threadIdx.x;
  if (w >= HIST_WORDS) return;
  unsigned run = 0;
#pragma unroll 8
  for (int b = 0; b < HIST_BLKS; ++b) {
    unsigned v = partial[(size_t)b * HIST_WORDS + w];
    partial[(size_t)b * HIST_WORDS + w] = run;
    run += v;
  }
  *(int4*)&counts[4 * w] = make_int4((int)(run & 255u), (int)((run >> 8) & 255u),
                                     (int)((run >> 16) & 255u), (int)(run >> 24));
}

__global__ void k_scan1(const int* __restrict__ counts, int* __restrict__ incl,
                        int* __restrict__ btot) {
  __shared__ int lds[TPB];
  int i = blockIdx.x * TPB + threadIdx.x;
  int v = (i < NN) ? counts[i] : 0;
  lds[threadIdx.x] = v;
  __syncthreads();
  for (int off = 1; off < TPB; off <<= 1) {
    int t = (threadIdx.x >= off) ? lds[threadIdx.x - off] : 0;
    __syncthreads();
    lds[threadIdx.x] += t;
    __syncthreads();
  }
  if (i < NN) incl[i] = lds[threadIdx.x];
  if (threadIdx.x == TPB - 1) btot[blockIdx.x] = lds[TPB - 1];
}

__global__ void k_scan23(const int* __restrict__ incl, const int* __restrict__ btot,
                         int* __restrict__ row_ptr) {
  __shared__ int lds[TPB];
  const int t = threadIdx.x, b = blockIdx.x;
  lds[t] = (t < 196 && t < b) ? btot[t] : 0;
  __syncthreads();
  for (int off = TPB / 2; off > 0; off >>= 1) {
    if (t < off) lds[t] += lds[t + off];
    __syncthreads();
  }
  int S = lds[0];
  int i = b * TPB + t;
  if (i == 0) row_ptr[0] = 0;
  if (i < NN) row_ptr[i + 1] = incl[i] + S;
}

// Atomic-free fill + embed (r12 structure).
__global__ __launch_bounds__(TPB) void k_fill_embed(
    const int* __restrict__ src, const int* __restrict__ dst,
    const unsigned* __restrict__ partial, const unsigned char* __restrict__ rank8,
    const int* __restrict__ row_ptr, unsigned short* __restrict__ srcs,
    const int* __restrict__ x, const float* __restrict__ emb,
    unsigned* __restrict__ h_bf) {
  __shared__ unsigned pref[HIST_WORDS];
  int b = blockIdx.x;
  if (b < HIST_BLKS) {
    const unsigned* pp = partial + (size_t)b * HIST_WORDS;
    for (int w = threadIdx.x; w < HIST_WORDS; w += TPB) pref[w] = pp[w];
    __syncthreads();
    const int* dp = dst + b * HIST_EPB;
    const int* sp = src + b * HIST_EPB;
    const unsigned char* rp = rank8 + b * HIST_EPB;
    for (int it = threadIdx.x; it < HIST_EPB; it += TPB) {
      int d = dp[it];
      unsigned base = (pref[d >> 2] >> (8u * (d & 3))) & 255u;
      int pos = row_ptr[d] + (int)base + (int)rp[it];
      srcs[pos] = (unsigned short)sp[it];
    }
  } else {
    int i = (b - HIST_BLKS) * TPB + threadIdx.x;
    int n = i >> 5, l = i & 31;
    float2 ev = *(const float2*)&emb[x[n] * 64 + 2 * l];
    h_bf[i] = f2bf(ev.x) | (f2bf(ev.y) << 16);
  }
}

// Aggregate over bf16 h, optional BN affine folded in -> packed bf16.
template <bool BN>
__global__ void k_aggregate_bf(const unsigned* __restrict__ h_bf,
                               const int* __restrict__ row_ptr,
                               const unsigned short* __restrict__ srcs,
                               const float* __restrict__ bnst,
                               unsigned* __restrict__ zb) {
  int wid = (blockIdx.x * TPB + threadIdx.x) >> 6;
  int lane = threadIdx.x & 63;
  if (wid >= NN) return;
  int half = lane >> 5, l = lane & 31;
  int beg = row_ptr[wid], end = row_ptr[wid + 1];
  float a0 = 0.f, a1 = 0.f;
  if (half == 0) {
    unsigned u = h_bf[(size_t)wid * 32 + l];
    a0 = bf2f(u & 0xFFFF);
    a1 = bf2f(u >> 16);
  }
  int e = beg + half;
  for (; e + 6 < end; e += 8) {
    int s0 = srcs[e], s1 = srcs[e + 2], s2 = srcs[e + 4], s3 = srcs[e + 6];
    unsigned u0 = h_bf[(size_t)s0 * 32 + l];
    unsigned u1 = h_bf[(size_t)s1 * 32 + l];
    unsigned u2 = h_bf[(size_t)s2 * 32 + l];
    unsigned u3 = h_bf[(size_t)s3 * 32 + l];
    a0 += (bf2f(u0 & 0xFFFF) + bf2f(u1 & 0xFFFF)) +
          (bf2f(u2 & 0xFFFF) + bf2f(u3 & 0xFFFF));
    a1 += (bf2f(u0 >> 16) + bf2f(u1 >> 16)) + (bf2f(u2 >> 16) + bf2f(u3 >> 16));
  }
  for (; e < end; e += 2) {
    unsigned u = h_bf[(size_t)srcs[e] * 32 + l];
    a0 += bf2f(u & 0xFFFF);
    a1 += bf2f(u >> 16);
  }
  a0 += __shfl_xor(a0, 32);
  a1 += __shfl_xor(a1, 32);
  if (half == 0) {
    float zv0, zv1;
    if constexpr (BN) {
      float2 scv = *(const float2*)&bnst[2 * l];
      float2 shv = *(const float2*)&bnst[64 + 2 * l];
      float d1 = (float)(1 + end - beg);
      zv0 = fmaf(scv.x, a0, d1 * shv.x);
      zv1 = fmaf(scv.y, a1, d1 * shv.y);
    } else {
      zv0 = a0;
      zv1 = a1;
    }
    zb[(size_t)wid * 32 + l] = f2bf(zv0) | (f2bf(zv1) << 16);
  }
}

// MFMA GEMM1: z2[N,128] = z[N,64] @ W[64,128] + b1 (bf16 in/out, f32 acc),
// per-block column stats. 64 rows/block, 4 waves; wave w owns rows 16w..16w+16.
// A frag (lane l): A[l&15][8*(l>>4)+i] loaded straight from global zb.
// B staged in LDS as bf16 [n][k] (stride 72 u16 => 16B-aligned ds_read_b128).
// C/D layout: col=lane&15, row=(lane>>4)*4+reg.
__global__ __launch_bounds__(TPB) void k_gemm1(const unsigned short* __restrict__ zb,
                                               const float* __restrict__ W,
                                               const float* __restrict__ bias,
                                               unsigned short* __restrict__ z2b,
                                               float* __restrict__ partials) {
  __shared__ __align__(16) unsigned short WTl[128 * 72];  // 18KB; reused for stats
  const int t = threadIdx.x;
  const int r0 = blockIdx.x * 64;
#pragma unroll
  for (int it = 0; it < 8192 / TPB; ++it) {
    int idx = t + it * TPB;            // W row-major [64][128]: k=idx>>7, n=idx&127
    WTl[(idx & 127) * 72 + (idx >> 7)] = (unsigned short)f2bf(W[idx]);
  }
  __syncthreads();

  const int w = t >> 6, lane = t & 63;
  const int m16 = lane & 15, kg = lane >> 4;
  const int ra = r0 + w * 16 + m16;
  bf16x8 a0 = {0, 0, 0, 0, 0, 0, 0, 0}, a1 = {0, 0, 0, 0, 0, 0, 0, 0};
  if (ra < NN) {
    a0 = *(const bf16x8*)&zb[(size_t)ra * 64 + kg * 8];
    a1 = *(const bf16x8*)&zb[(size_t)ra * 64 + 32 + kg * 8];
  }
  f32x4 acc[8];
#pragma unroll
  for (int f = 0; f < 8; ++f) acc[f] = f32x4{0.f, 0.f, 0.f, 0.f};
#pragma unroll
  for (int f = 0; f < 8; ++f) {
    bf16x8 b0 = *(const bf16x8*)&WTl[(f * 16 + m16) * 72 + kg * 8];
    bf16x8 b1 = *(const bf16x8*)&WTl[(f * 16 + m16) * 72 + 32 + kg * 8];
    acc[f] = __builtin_amdgcn_mfma_f32_16x16x32_bf16(a0, b0, acc[f], 0, 0, 0);
    acc[f] = __builtin_amdgcn_mfma_f32_16x16x32_bf16(a1, b1, acc[f], 0, 0, 0);
  }
  __syncthreads();  // WTl no longer needed; reuse as stats scratch
  float* Ss = (float*)WTl;   // [4][128]
  float* Sq = Ss + 512;      // [4][128]
  const int rwb = r0 + w * 16 + kg * 4;
#pragma unroll
  for (int f = 0; f < 8; ++f) {
    int col = f * 16 + m16;
    float bc = bias[col];
    float cs = 0.f, cq = 0.f;
#pragma unroll
    for (int j = 0; j < 4; ++j) {
      int rw = rwb + j;
      if (rw < NN) {
        float v = acc[f][j] + bc;
        z2b[(size_t)rw * 128 + col] = (unsigned short)f2bf(v);
        cs += v;
        cq += v * v;
      }
    }
    cs += __shfl_xor(cs, 16); cs += __shfl_xor(cs, 32);
    cq += __shfl_xor(cq, 16); cq += __shfl_xor(cq, 32);
    if (kg == 0) {
      Ss[w * 128 + col] = cs;
      Sq[w * 128 + col] = cq;
    }
  }
  __syncthreads();
  if (t < 128) {
    float ss = Ss[t] + Ss[128 + t] + Ss[256 + t] + Ss[384 + t];
    float qq = Sq[t] + Sq[128 + t] + Sq[256 + t] + Sq[384 + t];
    partials[blockIdx.x * 256 + t] = ss;
    partials[blockIdx.x * 256 + 128 + t] = qq;
  }
}

// MFMA GEMM2: h[N,64] = relu( relu(bn1(z2)) @ W[128,64] + b2 ), bf16 in/out.
// BN affine + relu applied in-register while building A fragments.
template <bool STATS>
__global__ __launch_bounds__(TPB) void k_gemm2(const unsigned short* __restrict__ z2b,
                                               const float* __restrict__ W,
                                               const float* __restrict__ bias,
                                               const float* __restrict__ bnst,
                                               unsigned short* __restrict__ outp,
                                               float* __restrict__ partials) {
  __shared__ __align__(16) unsigned short WTl[64 * 136];  // 17.4KB; reused for stats
  __shared__ float scl[128], shl[128];
  const int t = threadIdx.x;
  const int r0 = blockIdx.x * 64;
#pragma unroll
  for (int it = 0; it < 8192 / TPB; ++it) {
    int idx = t + it * TPB;            // W row-major [128][64]: k=idx>>6, n=idx&63
    WTl[(idx & 63) * 136 + (idx >> 6)] = (unsigned short)f2bf(W[idx]);
  }
  if (t < 128) {
    scl[t] = bnst[t];
    shl[t] = bnst[128 + t];
  }
  __syncthreads();

  const int w = t >> 6, lane = t & 63;
  const int m16 = lane & 15, kg = lane >> 4;
  const int ra = r0 + w * 16 + m16;
  f32x4 acc[4];
#pragma unroll
  for (int f = 0; f < 4; ++f) acc[f] = f32x4{0.f, 0.f, 0.f, 0.f};
#pragma unroll
  for (int s = 0; s < 4; ++s) {
    int k0 = s * 32 + kg * 8;
    bf16x8 a = {0, 0, 0, 0, 0, 0, 0, 0};
    if (ra < NN) {
      bf16x8 raw = *(const bf16x8*)&z2b[(size_t)ra * 128 + k0];
#pragma unroll
      for (int i = 0; i < 8; ++i) {
        float v = bf2f((unsigned)(unsigned short)raw[i]);
        v = fmaxf(fmaf(v, scl[k0 + i], shl[k0 + i]), 0.f);
        a[i] = (short)f2bf(v);
      }
    }
#pragma unroll
    for (int f = 0; f < 4; ++f) {
      bf16x8 b = *(const bf16x8*)&WTl[(f * 16 + m16) * 136 + k0];
      acc[f] = __builtin_amdgcn_mfma_f32_16x16x32_bf16(a, b, acc[f], 0, 0, 0);
    }
  }
  __syncthreads();
  float* Ss = (float*)WTl;  // [4][64]
  float* Sq = Ss + 256;
  const int rwb = r0 + w * 16 + kg * 4;
#pragma unroll
  for (int f = 0; f < 4; ++f) {
    int col = f * 16 + m16;
    float bc = bias[col];
    float cs = 0.f, cq = 0.f;
#pragma unroll
    for (int j = 0; j < 4; ++j) {
      int rw = rwb + j;
      if (rw < NN) {
        float v = fmaxf(acc[f][j] + bc, 0.f);
        outp[(size_t)rw * 64 + col] = (unsigned short)f2bf(v);
        if constexpr (STATS) {
          cs += v;
          cq += v * v;
        }
      }
    }
    if constexpr (STATS) {
      cs += __shfl_xor(cs, 16); cs += __shfl_xor(cs, 32);
      cq += __shfl_xor(cq, 16); cq += __shfl_xor(cq, 32);
      if (kg == 0) {
        Ss[w * 64 + col] = cs;
        Sq[w * 64 + col] = cq;
      }
    }
  }
  if constexpr (STATS) {
    __syncthreads();
    if (t < 64) {
      float ss = Ss[t] + Ss[64 + t] + Ss[128 + t] + Ss[192 + t];
      float qq = Sq[t] + Sq[64 + t] + Sq[128 + t] + Sq[192 + t];
      partials[blockIdx.x * 128 + t] = ss;
      partials[blockIdx.x * 128 + 64 + t] = qq;
    }
  }
}

// Fold partials: constant trip count + unroll-8 (r8 fix), LDS tree-fold.
template <int C>
__global__ __launch_bounds__(TPB_FIN) void k_finalize(const float* __restrict__ partials,
                                                      const float* __restrict__ gamma,
                                                      const float* __restrict__ beta,
                                                      float* __restrict__ out) {
  constexpr int G = TPB_FIN / C;
  constexpr int IT = NBLK_G / G;
  __shared__ float lds[2 * TPB_FIN];
  const int c = threadIdx.x % C, g = threadIdx.x / C;
  const float* p = partials + g * 2 * C + c;
  float s = 0.f, s2 = 0.f;
#pragma unroll 8
  for (int bb = 0; bb < IT; ++bb) {
    s += p[(size_t)bb * G * 2 * C];
    s2 += p[(size_t)bb * G * 2 * C + C];
  }
  lds[threadIdx.x] = s;
  lds[TPB_FIN + threadIdx.x] = s2;
  __syncthreads();
  if (g == 0) {
#pragma unroll
    for (int k = 1; k < G; ++k) {
      s += lds[k * C + c];
      s2 += lds[TPB_FIN + k * C + c];
    }
    float invN = 1.0f / NN;
    float mu = s * invN;
    float var = s2 * invN - mu * mu;
    float rs = rsqrtf(var + BN_EPS) * gamma[c];
    out[c] = rs;
    out[C + c] = beta[c] - mu * rs;
  }
}

// Fused pool + head: block per graph.
__global__ void k_poolhead(const unsigned* __restrict__ h_bf,
                           const int* __restrict__ batch,
                           const float* __restrict__ Wh1, const float* __restrict__ bh1,
                           const float* __restrict__ Wh2, const float* __restrict__ bh2,
                           float* __restrict__ out) {
  __shared__ float lds[2 * TPB];
  __shared__ float gl[64];
  __shared__ float hidl[32];
  int gi = blockIdx.x;
  int col = threadIdx.x & 31, grp = threadIdx.x >> 5;
  int a = 0, b = NN;
  while (a < b) { int m = (a + b) >> 1; if (batch[m] < gi) a = m + 1; else b = m; }
  int lo = a;
  b = NN;
  while (a < b) { int m = (a + b) >> 1; if (batch[m] < gi + 1) a = m + 1; else b = m; }
  int hi = a;
  float a0 = 0.f, a1 = 0.f;
  for (int n = lo + grp; n < hi; n += 8) {
    unsigned u = h_bf[(size_t)n * 32 + col];
    a0 += bf2f(u & 0xFFFF);
    a1 += bf2f(u >> 16);
  }
  lds[threadIdx.x] = a0;
  lds[TPB + threadIdx.x] = a1;
  __syncthreads();
  if (grp == 0) {
#pragma unroll
    for (int k = 1; k < 8; ++k) {
      a0 += lds[k * 32 + col];
      a1 += lds[TPB + k * 32 + col];
    }
    gl[2 * col] = a0;
    gl[2 * col + 1] = a1;
  }
  __syncthreads();
  if (threadIdx.x < 32) {
    int j = threadIdx.x;
    float hid = bh1[j];
    for (int k = 0; k < 64; ++k) hid = fmaf(gl[k], Wh1[k * 32 + j], hid);
    hidl[j] = fmaxf(hid, 0.f);
  }
  __syncthreads();
  if (threadIdx.x < 10) {
    int j = threadIdx.x;
    float o = bh2[j];
#pragma unroll
    for (int k = 0; k < 32; ++k) o = fmaf(hidl[k], Wh2[k * 10 + j], o);
    out[gi * 10 + j] = o;
  }
}

extern "C" void kernel_launch(void* const* d_in, const int* in_sizes, int n_in,
                              void* d_out, int out_size, void* d_ws, size_t ws_size,
                              hipStream_t stream) {
  const int* x = (const int*)d_in[0];
  const int* ei = (const int*)d_in[1];
  const int* batch = (const int*)d_in[2];
  const float* emb = (const float*)d_in[3];
  const float* W1 = (const float*)d_in[4];
  const float* b1 = (const float*)d_in[5];
  const float* g1 = (const float*)d_in[6];
  const float* bt1 = (const float*)d_in[7];
  const float* W2 = (const float*)d_in[8];
  const float* b2 = (const float*)d_in[9];
  const float* gbn = (const float*)d_in[10];
  const float* bbn = (const float*)d_in[11];
  const float* Wh1 = (const float*)d_in[12];
  const float* bh1 = (const float*)d_in[13];
  const float* Wh2 = (const float*)d_in[14];
  const float* bh2 = (const float*)d_in[15];
  float* out = (float*)d_out;

  const int* e_src = ei;
  const int* e_dst = ei + NE;

  char* ws = (char*)d_ws;
  size_t off = 0;
  auto alloc = [&](size_t bytes) -> void* {
    void* p = ws + off;
    off = (off + bytes + 255) & ~(size_t)255;
    return p;
  };
  unsigned* h_bf = (unsigned*)alloc((size_t)NN * 64 * 2);
  unsigned* zb = (unsigned*)alloc((size_t)NN * 64 * 2);
  unsigned short* z2b = (unsigned short*)alloc((size_t)NN * 128 * 2);
  unsigned short* srcs = (unsigned short*)alloc((size_t)NE * 2);
  unsigned char* rank8 = (unsigned char*)alloc((size_t)NE);
  int* row_ptr = (int*)alloc((size_t)(NN + 1) * 4);
  int* incl = (int*)alloc((size_t)NN * 4);
  int* btot = (int*)alloc(256 * 4);
  float* partials = (float*)alloc((size_t)NBLK_G * 256 * 4);
  float* statsL = (float*)alloc(4 * 256 * 4);
  float* statsH = (float*)alloc(3 * 128 * 4);
  int* counts = (int*)alloc((size_t)NN * 4);
  unsigned* histpart = (unsigned*)alloc((size_t)HIST_BLKS * HIST_WORDS * 4);

  k_hist_lds<<<HIST_BLKS, TPB, 0, stream>>>(e_dst, histpart, rank8);
  k_hist_scan<<<(HIST_WORDS + TPB - 1) / TPB, TPB, 0, stream>>>(histpart, counts);

  int nScanBlocks = (NN + TPB - 1) / TPB;  // 196
  k_scan1<<<nScanBlocks, TPB, 0, stream>>>(counts, incl, btot);
  k_scan23<<<nScanBlocks, TPB, 0, stream>>>(incl, btot, row_ptr);
  k_fill_embed<<<HIST_BLKS + EMB_BLKS, TPB, 0, stream>>>(e_src, e_dst, histpart, rank8,
                                                         row_ptr, srcs, x, emb, h_bf);

  int gAgg = (NN * 64 + TPB - 1) / TPB;  // 12500 (wave per node)

  for (int i = 0; i < 4; ++i) {
    const float* W1i = W1 + (size_t)i * 64 * 128;
    const float* b1i = b1 + (size_t)i * 128;
    const float* g1i = g1 + (size_t)i * 128;
    const float* bt1i = bt1 + (size_t)i * 128;
    const float* W2i = W2 + (size_t)i * 128 * 64;
    const float* b2i = b2 + (size_t)i * 64;
    float* stL = statsL + (size_t)i * 256;

    if (i == 0)
      k_aggregate_bf<false><<<gAgg, TPB, 0, stream>>>(h_bf, row_ptr, srcs, nullptr, zb);
    else
      k_aggregate_bf<true><<<gAgg, TPB, 0, stream>>>(h_bf, row_ptr, srcs,
                                                     statsH + (size_t)(i - 1) * 128, zb);

    k_gemm1<<<NBLK_G, TPB, 0, stream>>>((const unsigned short*)zb, W1i, b1i, z2b, partials);
    k_finalize<128><<<1, TPB_FIN, 0, stream>>>(partials, g1i, bt1i, stL);

    if (i < 3) {
      float* stH = statsH + (size_t)i * 128;
      k_gemm2<true><<<NBLK_G, TPB, 0, stream>>>(z2b, W2i, b2i, stL,
                                                (unsigned short*)h_bf, partials);
      k_finalize<64><<<1, TPB_FIN, 0, stream>>>(partials, gbn + (size_t)i * 64,
                                                bbn + (size_t)i * 64, stH);
    } else {
      k_gemm2<false><<<NBLK_G, TPB, 0, stream>>>(z2b, W2i, b2i, stL,
                                                 (unsigned short*)h_bf, partials);
    }
  }

  k_poolhead<<<NG, TPB, 0, stream>>>(h_bf, batch, Wh1, bh1, Wh2, bh2, out);
}

// Round 14
// 372.454 us; speedup vs baseline: 1.3564x; 1.0207x over previous
//
#include <hip/hip_runtime.h>

#define NN 50000
#define NE 800000
#define NG 512
#define TPB 256
#define BN_EPS 1e-5f
#define NBLK_G 784       // GEMM grid: ceil(NN/64)=782, padded to 784 so finalize
                         // trip count is a compile-time constant
#define EDGE_BLKS 3125   // NE/TPB exactly
#define EMB_BLKS 6250    // NN*32/TPB exactly
#define HIST_BLKS 128
#define HIST_EPB 6250    // NE/HIST_BLKS
#define HIST_WORDS 12500 // NN/4 packed u8x4 words
#define TPB_FIN 512

typedef __attribute__((ext_vector_type(8))) short bf16x8;
typedef __attribute__((ext_vector_type(4))) float f32x4;

__device__ __forceinline__ float bf2f(unsigned u) {  // low 16 bits = bf16
  return __uint_as_float(u << 16);
}
__device__ __forceinline__ unsigned f2bf(float f) {
  unsigned u = __float_as_uint(f);
  u += 0x7FFFu + ((u >> 16) & 1u);  // round-to-nearest-even
  return u >> 16;
}

// Pass 1: per-block LDS-privatized histogram + per-edge within-block rank.
__global__ __launch_bounds__(TPB) void k_hist_lds(const int* __restrict__ dst,
                                                  unsigned* __restrict__ partial,
                                                  unsigned char* __restrict__ rank8) {
  __shared__ unsigned hist[HIST_WORDS];
  const int t = threadIdx.x, b = blockIdx.x;
  for (int w = t; w < HIST_WORDS; w += TPB) hist[w] = 0u;
  __syncthreads();
  const int* dp = dst + b * HIST_EPB;
  unsigned char* rp = rank8 + b * HIST_EPB;
  for (int it = t; it < HIST_EPB; it += TPB) {
    int d = dp[it];
    unsigned sh = 8u * (d & 3);
    unsigned old = atomicAdd(&hist[d >> 2], 1u << sh);
    rp[it] = (unsigned char)((old >> sh) & 255u);
  }
  __syncthreads();
  unsigned* out = partial + (size_t)b * HIST_WORDS;
  for (int w = t; w < HIST_WORDS; w += TPB) out[w] = hist[w];
}

// Pass 2: exclusive prefix over the HIST_BLKS block histograms in place
// (packed u8 lanes, degree < 255 so no carries); emit total counts.
__global__ void k_hist_scan(unsigned* __restrict__ partial, int* __restrict__ counts) {
  int w = blockIdx.x * TPB + threadIdx.x;
  if (w >= HIST_WORDS) return;
  unsigned run = 0;
#pragma unroll 8
  for (int b = 0; b < HIST_BLKS; ++b) {
    unsigned v = partial[(size_t)b * HIST_WORDS + w];
    partial[(size_t)b * HIST_WORDS + w] = run;
    run += v;
  }
  *(int4*)&counts[4 * w] = make_int4((int)(run & 255u), (int)((run >> 8) & 255u),
                                     (int)((run >> 16) & 255u), (int)(run >> 24));
}

__global__ void k_scan1(const int* __restrict__ counts, int* __restrict__ incl,
                        int* __restrict__ btot) {
  __shared__ int lds[TPB];
  int i = blockIdx.x * TPB + threadIdx.x;
  int v = (i < NN) ? counts[i] : 0;
  lds[threadIdx.x] = v;
  __syncthreads();
  for (int off = 1; off < TPB; off <<= 1) {
    int t = (threadIdx.x >= off) ? lds[threadIdx.x - off] : 0;
    __syncthreads();
    lds[threadIdx.x] += t;
    __syncthreads();
  }
  if (i < NN) incl[i] = lds[threadIdx.x];
  if (threadIdx.x == TPB - 1) btot[blockIdx.x] = lds[TPB - 1];
}

__global__ void k_scan23(const int* __restrict__ incl, const int* __restrict__ btot,
                         int* __restrict__ row_ptr) {
  __shared__ int lds[TPB];
  const int t = threadIdx.x, b = blockIdx.x;
  lds[t] = (t < 196 && t < b) ? btot[t] : 0;
  __syncthreads();
  for (int off = TPB / 2; off > 0; off >>= 1) {
    if (t < off) lds[t] += lds[t + off];
    __syncthreads();
  }
  int S = lds[0];
  int i = b * TPB + t;
  if (i == 0) row_ptr[0] = 0;
  if (i < NN) row_ptr[i + 1] = incl[i] + S;
}

// LDS-free atomic-free fill + embed at full occupancy (r13's merged kernel
// allocated 50KB LDS for ALL blocks -> 7.5% occupancy; the prefix is now
// gathered per-edge from L2-resident histpart instead).
// Blocks [0,EDGE_BLKS): pos = row_ptr[d] + prefixbyte(histpart[e/HIST_EPB][d])
//                            + rank8[e]; scatter src as ushort.
// Blocks [EDGE_BLKS,..): h_bf[n] = bf16(emb[x[n]]).
__global__ __launch_bounds__(TPB) void k_fill_embed(
    const int* __restrict__ src, const int* __restrict__ dst,
    const unsigned* __restrict__ partial, const unsigned char* __restrict__ rank8,
    const int* __restrict__ row_ptr, unsigned short* __restrict__ srcs,
    const int* __restrict__ x, const float* __restrict__ emb,
    unsigned* __restrict__ h_bf) {
  int b = blockIdx.x;
  if (b < EDGE_BLKS) {
    int e = b * TPB + threadIdx.x;
    int d = dst[e];
    int bh = e / HIST_EPB;
    unsigned base = (partial[(size_t)bh * HIST_WORDS + (d >> 2)] >> (8u * (d & 3))) & 255u;
    int pos = row_ptr[d] + (int)base + (int)rank8[e];
    srcs[pos] = (unsigned short)src[e];
  } else {
    int i = (b - EDGE_BLKS) * TPB + threadIdx.x;  // < NN*32 exactly
    int n = i >> 5, l = i & 31;
    float2 ev = *(const float2*)&emb[x[n] * 64 + 2 * l];
    h_bf[i] = f2bf(ev.x) | (f2bf(ev.y) << 16);
  }
}

// Aggregate over bf16 h, optional BN affine folded in -> packed bf16.
template <bool BN>
__global__ void k_aggregate_bf(const unsigned* __restrict__ h_bf,
                               const int* __restrict__ row_ptr,
                               const unsigned short* __restrict__ srcs,
                               const float* __restrict__ bnst,
                               unsigned* __restrict__ zb) {
  int wid = (blockIdx.x * TPB + threadIdx.x) >> 6;
  int lane = threadIdx.x & 63;
  if (wid >= NN) return;
  int half = lane >> 5, l = lane & 31;
  int beg = row_ptr[wid], end = row_ptr[wid + 1];
  float a0 = 0.f, a1 = 0.f;
  if (half == 0) {
    unsigned u = h_bf[(size_t)wid * 32 + l];
    a0 = bf2f(u & 0xFFFF);
    a1 = bf2f(u >> 16);
  }
  int e = beg + half;
  for (; e + 6 < end; e += 8) {
    int s0 = srcs[e], s1 = srcs[e + 2], s2 = srcs[e + 4], s3 = srcs[e + 6];
    unsigned u0 = h_bf[(size_t)s0 * 32 + l];
    unsigned u1 = h_bf[(size_t)s1 * 32 + l];
    unsigned u2 = h_bf[(size_t)s2 * 32 + l];
    unsigned u3 = h_bf[(size_t)s3 * 32 + l];
    a0 += (bf2f(u0 & 0xFFFF) + bf2f(u1 & 0xFFFF)) +
          (bf2f(u2 & 0xFFFF) + bf2f(u3 & 0xFFFF));
    a1 += (bf2f(u0 >> 16) + bf2f(u1 >> 16)) + (bf2f(u2 >> 16) + bf2f(u3 >> 16));
  }
  for (; e < end; e += 2) {
    unsigned u = h_bf[(size_t)srcs[e] * 32 + l];
    a0 += bf2f(u & 0xFFFF);
    a1 += bf2f(u >> 16);
  }
  a0 += __shfl_xor(a0, 32);
  a1 += __shfl_xor(a1, 32);
  if (half == 0) {
    float zv0, zv1;
    if constexpr (BN) {
      float2 scv = *(const float2*)&bnst[2 * l];
      float2 shv = *(const float2*)&bnst[64 + 2 * l];
      float d1 = (float)(1 + end - beg);
      zv0 = fmaf(scv.x, a0, d1 * shv.x);
      zv1 = fmaf(scv.y, a1, d1 * shv.y);
    } else {
      zv0 = a0;
      zv1 = a1;
    }
    zb[(size_t)wid * 32 + l] = f2bf(zv0) | (f2bf(zv1) << 16);
  }
}

// MFMA GEMM1: z2[N,128] = z[N,64] @ W[64,128] + b1 (bf16 in/out, f32 acc),
// per-block column stats. C/D layout: col=lane&15, row=(lane>>4)*4+reg.
__global__ __launch_bounds__(TPB) void k_gemm1(const unsigned short* __restrict__ zb,
                                               const float* __restrict__ W,
                                               const float* __restrict__ bias,
                                               unsigned short* __restrict__ z2b,
                                               float* __restrict__ partials) {
  __shared__ __align__(16) unsigned short WTl[128 * 72];  // 18KB; reused for stats
  const int t = threadIdx.x;
  const int r0 = blockIdx.x * 64;
#pragma unroll
  for (int it = 0; it < 8192 / TPB; ++it) {
    int idx = t + it * TPB;            // W row-major [64][128]: k=idx>>7, n=idx&127
    WTl[(idx & 127) * 72 + (idx >> 7)] = (unsigned short)f2bf(W[idx]);
  }
  __syncthreads();

  const int w = t >> 6, lane = t & 63;
  const int m16 = lane & 15, kg = lane >> 4;
  const int ra = r0 + w * 16 + m16;
  bf16x8 a0 = {0, 0, 0, 0, 0, 0, 0, 0}, a1 = {0, 0, 0, 0, 0, 0, 0, 0};
  if (ra < NN) {
    a0 = *(const bf16x8*)&zb[(size_t)ra * 64 + kg * 8];
    a1 = *(const bf16x8*)&zb[(size_t)ra * 64 + 32 + kg * 8];
  }
  f32x4 acc[8];
#pragma unroll
  for (int f = 0; f < 8; ++f) acc[f] = f32x4{0.f, 0.f, 0.f, 0.f};
#pragma unroll
  for (int f = 0; f < 8; ++f) {
    bf16x8 b0 = *(const bf16x8*)&WTl[(f * 16 + m16) * 72 + kg * 8];
    bf16x8 b1 = *(const bf16x8*)&WTl[(f * 16 + m16) * 72 + 32 + kg * 8];
    acc[f] = __builtin_amdgcn_mfma_f32_16x16x32_bf16(a0, b0, acc[f], 0, 0, 0);
    acc[f] = __builtin_amdgcn_mfma_f32_16x16x32_bf16(a1, b1, acc[f], 0, 0, 0);
  }
  __syncthreads();  // WTl no longer needed; reuse as stats scratch
  float* Ss = (float*)WTl;   // [4][128]
  float* Sq = Ss + 512;      // [4][128]
  const int rwb = r0 + w * 16 + kg * 4;
#pragma unroll
  for (int f = 0; f < 8; ++f) {
    int col = f * 16 + m16;
    float bc = bias[col];
    float cs = 0.f, cq = 0.f;
#pragma unroll
    for (int j = 0; j < 4; ++j) {
      int rw = rwb + j;
      if (rw < NN) {
        float v = acc[f][j] + bc;
        z2b[(size_t)rw * 128 + col] = (unsigned short)f2bf(v);
        cs += v;
        cq += v * v;
      }
    }
    cs += __shfl_xor(cs, 16); cs += __shfl_xor(cs, 32);
    cq += __shfl_xor(cq, 16); cq += __shfl_xor(cq, 32);
    if (kg == 0) {
      Ss[w * 128 + col] = cs;
      Sq[w * 128 + col] = cq;
    }
  }
  __syncthreads();
  if (t < 128) {
    float ss = Ss[t] + Ss[128 + t] + Ss[256 + t] + Ss[384 + t];
    float qq = Sq[t] + Sq[128 + t] + Sq[256 + t] + Sq[384 + t];
    partials[blockIdx.x * 256 + t] = ss;
    partials[blockIdx.x * 256 + 128 + t] = qq;
  }
}

// MFMA GEMM2: h[N,64] = relu( relu(bn1(z2)) @ W[128,64] + b2 ), bf16 in/out.
template <bool STATS>
__global__ __launch_bounds__(TPB) void k_gemm2(const unsigned short* __restrict__ z2b,
                                               const float* __restrict__ W,
                                               const float* __restrict__ bias,
                                               const float* __restrict__ bnst,
                                               unsigned short* __restrict__ outp,
                                               float* __restrict__ partials) {
  __shared__ __align__(16) unsigned short WTl[64 * 136];  // 17.4KB; reused for stats
  __shared__ float scl[128], shl[128];
  const int t = threadIdx.x;
  const int r0 = blockIdx.x * 64;
#pragma unroll
  for (int it = 0; it < 8192 / TPB; ++it) {
    int idx = t + it * TPB;            // W row-major [128][64]: k=idx>>6, n=idx&63
    WTl[(idx & 63) * 136 + (idx >> 6)] = (unsigned short)f2bf(W[idx]);
  }
  if (t < 128) {
    scl[t] = bnst[t];
    shl[t] = bnst[128 + t];
  }
  __syncthreads();

  const int w = t >> 6, lane = t & 63;
  const int m16 = lane & 15, kg = lane >> 4;
  const int ra = r0 + w * 16 + m16;
  f32x4 acc[4];
#pragma unroll
  for (int f = 0; f < 4; ++f) acc[f] = f32x4{0.f, 0.f, 0.f, 0.f};
#pragma unroll
  for (int s = 0; s < 4; ++s) {
    int k0 = s * 32 + kg * 8;
    bf16x8 a = {0, 0, 0, 0, 0, 0, 0, 0};
    if (ra < NN) {
      bf16x8 raw = *(const bf16x8*)&z2b[(size_t)ra * 128 + k0];
#pragma unroll
      for (int i = 0; i < 8; ++i) {
        float v = bf2f((unsigned)(unsigned short)raw[i]);
        v = fmaxf(fmaf(v, scl[k0 + i], shl[k0 + i]), 0.f);
        a[i] = (short)f2bf(v);
      }
    }
#pragma unroll
    for (int f = 0; f < 4; ++f) {
      bf16x8 b = *(const bf16x8*)&WTl[(f * 16 + m16) * 136 + k0];
      acc[f] = __builtin_amdgcn_mfma_f32_16x16x32_bf16(a, b, acc[f], 0, 0, 0);
    }
  }
  __syncthreads();
  float* Ss = (float*)WTl;  // [4][64]
  float* Sq = Ss + 256;
  const int rwb = r0 + w * 16 + kg * 4;
#pragma unroll
  for (int f = 0; f < 4; ++f) {
    int col = f * 16 + m16;
    float bc = bias[col];
    float cs = 0.f, cq = 0.f;
#pragma unroll
    for (int j = 0; j < 4; ++j) {
      int rw = rwb + j;
      if (rw < NN) {
        float v = fmaxf(acc[f][j] + bc, 0.f);
        outp[(size_t)rw * 64 + col] = (unsigned short)f2bf(v);
        if constexpr (STATS) {
          cs += v;
          cq += v * v;
        }
      }
    }
    if constexpr (STATS) {
      cs += __shfl_xor(cs, 16); cs += __shfl_xor(cs, 32);
      cq += __shfl_xor(cq, 16); cq += __shfl_xor(cq, 32);
      if (kg == 0) {
        Ss[w * 64 + col] = cs;
        Sq[w * 64 + col] = cq;
      }
    }
  }
  if constexpr (STATS) {
    __syncthreads();
    if (t < 64) {
      float ss = Ss[t] + Ss[64 + t] + Ss[128 + t] + Ss[192 + t];
      float qq = Sq[t] + Sq[64 + t] + Sq[128 + t] + Sq[192 + t];
      partials[blockIdx.x * 128 + t] = ss;
      partials[blockIdx.x * 128 + 64 + t] = qq;
    }
  }
}

// Fold partials: constant trip count + unroll-8 (r8 fix), LDS tree-fold.
template <int C>
__global__ __launch_bounds__(TPB_FIN) void k_finalize(const float* __restrict__ partials,
                                                      const float* __restrict__ gamma,
                                                      const float* __restrict__ beta,
                                                      float* __restrict__ out) {
  constexpr int G = TPB_FIN / C;
  constexpr int IT = NBLK_G / G;
  __shared__ float lds[2 * TPB_FIN];
  const int c = threadIdx.x % C, g = threadIdx.x / C;
  const float* p = partials + g * 2 * C + c;
  float s = 0.f, s2 = 0.f;
#pragma unroll 8
  for (int bb = 0; bb < IT; ++bb) {
    s += p[(size_t)bb * G * 2 * C];
    s2 += p[(size_t)bb * G * 2 * C + C];
  }
  lds[threadIdx.x] = s;
  lds[TPB_FIN + threadIdx.x] = s2;
  __syncthreads();
  if (g == 0) {
#pragma unroll
    for (int k = 1; k < G; ++k) {
      s += lds[k * C + c];
      s2 += lds[TPB_FIN + k * C + c];
    }
    float invN = 1.0f / NN;
    float mu = s * invN;
    float var = s2 * invN - mu * mu;
    float rs = rsqrtf(var + BN_EPS) * gamma[c];
    out[c] = rs;
    out[C + c] = beta[c] - mu * rs;
  }
}

// Fused pool + head: block per graph.
__global__ void k_poolhead(const unsigned* __restrict__ h_bf,
                           const int* __restrict__ batch,
                           const float* __restrict__ Wh1, const float* __restrict__ bh1,
                           const float* __restrict__ Wh2, const float* __restrict__ bh2,
                           float* __restrict__ out) {
  __shared__ float lds[2 * TPB];
  __shared__ float gl[64];
  __shared__ float hidl[32];
  int gi = blockIdx.x;
  int col = threadIdx.x & 31, grp = threadIdx.x >> 5;
  int a = 0, b = NN;
  while (a < b) { int m = (a + b) >> 1; if (batch[m] < gi) a = m + 1; else b = m; }
  int lo = a;
  b = NN;
  while (a < b) { int m = (a + b) >> 1; if (batch[m] < gi + 1) a = m + 1; else b = m; }
  int hi = a;
  float a0 = 0.f, a1 = 0.f;
  for (int n = lo + grp; n < hi; n += 8) {
    unsigned u = h_bf[(size_t)n * 32 + col];
    a0 += bf2f(u & 0xFFFF);
    a1 += bf2f(u >> 16);
  }
  lds[threadIdx.x] = a0;
  lds[TPB + threadIdx.x] = a1;
  __syncthreads();
  if (grp == 0) {
#pragma unroll
    for (int k = 1; k < 8; ++k) {
      a0 += lds[k * 32 + col];
      a1 += lds[TPB + k * 32 + col];
    }
    gl[2 * col] = a0;
    gl[2 * col + 1] = a1;
  }
  __syncthreads();
  if (threadIdx.x < 32) {
    int j = threadIdx.x;
    float hid = bh1[j];
    for (int k = 0; k < 64; ++k) hid = fmaf(gl[k], Wh1[k * 32 + j], hid);
    hidl[j] = fmaxf(hid, 0.f);
  }
  __syncthreads();
  if (threadIdx.x < 10) {
    int j = threadIdx.x;
    float o = bh2[j];
#pragma unroll
    for (int k = 0; k < 32; ++k) o = fmaf(hidl[k], Wh2[k * 10 + j], o);
    out[gi * 10 + j] = o;
  }
}

extern "C" void kernel_launch(void* const* d_in, const int* in_sizes, int n_in,
                              void* d_out, int out_size, void* d_ws, size_t ws_size,
                              hipStream_t stream) {
  const int* x = (const int*)d_in[0];
  const int* ei = (const int*)d_in[1];
  const int* batch = (const int*)d_in[2];
  const float* emb = (const float*)d_in[3];
  const float* W1 = (const float*)d_in[4];
  const float* b1 = (const float*)d_in[5];
  const float* g1 = (const float*)d_in[6];
  const float* bt1 = (const float*)d_in[7];
  const float* W2 = (const float*)d_in[8];
  const float* b2 = (const float*)d_in[9];
  const float* gbn = (const float*)d_in[10];
  const float* bbn = (const float*)d_in[11];
  const float* Wh1 = (const float*)d_in[12];
  const float* bh1 = (const float*)d_in[13];
  const float* Wh2 = (const float*)d_in[14];
  const float* bh2 = (const float*)d_in[15];
  float* out = (float*)d_out;

  const int* e_src = ei;
  const int* e_dst = ei + NE;

  char* ws = (char*)d_ws;
  size_t off = 0;
  auto alloc = [&](size_t bytes) -> void* {
    void* p = ws + off;
    off = (off + bytes + 255) & ~(size_t)255;
    return p;
  };
  unsigned* h_bf = (unsigned*)alloc((size_t)NN * 64 * 2);
  unsigned* zb = (unsigned*)alloc((size_t)NN * 64 * 2);
  unsigned short* z2b = (unsigned short*)alloc((size_t)NN * 128 * 2);
  unsigned short* srcs = (unsigned short*)alloc((size_t)NE * 2);
  unsigned char* rank8 = (unsigned char*)alloc((size_t)NE);
  int* row_ptr = (int*)alloc((size_t)(NN + 1) * 4);
  int* incl = (int*)alloc((size_t)NN * 4);
  int* btot = (int*)alloc(256 * 4);
  float* partials = (float*)alloc((size_t)NBLK_G * 256 * 4);
  float* statsL = (float*)alloc(4 * 256 * 4);
  float* statsH = (float*)alloc(3 * 128 * 4);
  int* counts = (int*)alloc((size_t)NN * 4);
  unsigned* histpart = (unsigned*)alloc((size_t)HIST_BLKS * HIST_WORDS * 4);

  k_hist_lds<<<HIST_BLKS, TPB, 0, stream>>>(e_dst, histpart, rank8);
  k_hist_scan<<<(HIST_WORDS + TPB - 1) / TPB, TPB, 0, stream>>>(histpart, counts);

  int nScanBlocks = (NN + TPB - 1) / TPB;  // 196
  k_scan1<<<nScanBlocks, TPB, 0, stream>>>(counts, incl, btot);
  k_scan23<<<nScanBlocks, TPB, 0, stream>>>(incl, btot, row_ptr);
  k_fill_embed<<<EDGE_BLKS + EMB_BLKS, TPB, 0, stream>>>(e_src, e_dst, histpart, rank8,
                                                         row_ptr, srcs, x, emb, h_bf);

  int gAgg = (NN * 64 + TPB - 1) / TPB;  // 12500 (wave per node)

  for (int i = 0; i < 4; ++i) {
    const float* W1i = W1 + (size_t)i * 64 * 128;
    const float* b1i = b1 + (size_t)i * 128;
    const float* g1i = g1 + (size_t)i * 128;
    const float* bt1i = bt1 + (size_t)i * 128;
    const float* W2i = W2 + (size_t)i * 128 * 64;
    const float* b2i = b2 + (size_t)i * 64;
    float* stL = statsL + (size_t)i * 256;

    if (i == 0)
      k_aggregate_bf<false><<<gAgg, TPB, 0, stream>>>(h_bf, row_ptr, srcs, nullptr, zb);
    else
      k_aggregate_bf<true><<<gAgg, TPB, 0, stream>>>(h_bf, row_ptr, srcs,
                                                     statsH + (size_t)(i - 1) * 128, zb);

    k_gemm1<<<NBLK_G, TPB, 0, stream>>>((const unsigned short*)zb, W1i, b1i, z2b, partials);
    k_finalize<128><<<1, TPB_FIN, 0, stream>>>(partials, g1i, bt1i, stL);

    if (i < 3) {
      float* stH = statsH + (size_t)i * 128;
      k_gemm2<true><<<NBLK_G, TPB, 0, stream>>>(z2b, W2i, b2i, stL,
                                                (unsigned short*)h_bf, partials);
      k_finalize<64><<<1, TPB_FIN, 0, stream>>>(partials, gbn + (size_t)i * 64,
                                                bbn + (size_t)i * 64, stH);
    } else {
      k_gemm2<false><<<NBLK_G, TPB, 0, stream>>>(z2b, W2i, b2i, stL,
                                                 (unsigned short*)h_bf, partials);
    }
  }

  k_poolhead<<<NG, TPB, 0, stream>>>(h_bf, batch, Wh1, bh1, Wh2, bh2, out);
}

// Round 15
// 308.075 us; speedup vs baseline: 1.6398x; 1.2090x over previous
//
#include <hip/hip_runtime.h>

#define NN 50000
#define NE 800000
#define NG 512
#define TPB 256
#define BN_EPS 1e-5f
#define NBLK_G 784       // GEMM grid: ceil(NN/64)=782, padded to 784 so finalize
                         // trip count is a compile-time constant
#define EDGE_BLKS 3125   // NE/TPB exactly
#define EMB_BLKS 6250    // NN*32/TPB exactly
#define HIST_BLKS 128
#define HIST_EPB 6250    // NE/HIST_BLKS
#define HIST_WORDS 12500 // NN/4 packed u8x4 words
#define TPB_FIN 1024

typedef __attribute__((ext_vector_type(8))) short bf16x8;
typedef __attribute__((ext_vector_type(4))) float f32x4;

__device__ __forceinline__ float bf2f(unsigned u) {  // low 16 bits = bf16
  return __uint_as_float(u << 16);
}
__device__ __forceinline__ unsigned f2bf(float f) {
  unsigned u = __float_as_uint(f);
  u += 0x7FFFu + ((u >> 16) & 1u);  // round-to-nearest-even
  return u >> 16;
}

// Pass 1: per-block LDS-privatized histogram + per-edge within-block rank.
__global__ __launch_bounds__(TPB) void k_hist_lds(const int* __restrict__ dst,
                                                  unsigned* __restrict__ partial,
                                                  unsigned char* __restrict__ rank8) {
  __shared__ unsigned hist[HIST_WORDS];
  const int t = threadIdx.x, b = blockIdx.x;
  for (int w = t; w < HIST_WORDS; w += TPB) hist[w] = 0u;
  __syncthreads();
  const int* dp = dst + b * HIST_EPB;
  unsigned char* rp = rank8 + b * HIST_EPB;
  for (int it = t; it < HIST_EPB; it += TPB) {
    int d = dp[it];
    unsigned sh = 8u * (d & 3);
    unsigned old = atomicAdd(&hist[d >> 2], 1u << sh);
    rp[it] = (unsigned char)((old >> sh) & 255u);
  }
  __syncthreads();
  unsigned* out = partial + (size_t)b * HIST_WORDS;
  for (int w = t; w < HIST_WORDS; w += TPB) out[w] = hist[w];
}

// Pass 2: exclusive prefix over the HIST_BLKS block histograms in place
// (packed u8 lanes, degree < 255 so no carries); emit total counts.
__global__ void k_hist_scan(unsigned* __restrict__ partial, int* __restrict__ counts) {
  int w = blockIdx.x * TPB + threadIdx.x;
  if (w >= HIST_WORDS) return;
  unsigned run = 0;
#pragma unroll 8
  for (int b = 0; b < HIST_BLKS; ++b) {
    unsigned v = partial[(size_t)b * HIST_WORDS + w];
    partial[(size_t)b * HIST_WORDS + w] = run;
    run += v;
  }
  *(int4*)&counts[4 * w] = make_int4((int)(run & 255u), (int)((run >> 8) & 255u),
                                     (int)((run >> 16) & 255u), (int)(run >> 24));
}

__global__ void k_scan1(const int* __restrict__ counts, int* __restrict__ incl,
                        int* __restrict__ btot) {
  __shared__ int lds[TPB];
  int i = blockIdx.x * TPB + threadIdx.x;
  int v = (i < NN) ? counts[i] : 0;
  lds[threadIdx.x] = v;
  __syncthreads();
  for (int off = 1; off < TPB; off <<= 1) {
    int t = (threadIdx.x >= off) ? lds[threadIdx.x - off] : 0;
    __syncthreads();
    lds[threadIdx.x] += t;
    __syncthreads();
  }
  if (i < NN) incl[i] = lds[threadIdx.x];
  if (threadIdx.x == TPB - 1) btot[blockIdx.x] = lds[TPB - 1];
}

__global__ void k_scan23(const int* __restrict__ incl, const int* __restrict__ btot,
                         int* __restrict__ row_ptr) {
  __shared__ int lds[TPB];
  const int t = threadIdx.x, b = blockIdx.x;
  lds[t] = (t < 196 && t < b) ? btot[t] : 0;
  __syncthreads();
  for (int off = TPB / 2; off > 0; off >>= 1) {
    if (t < off) lds[t] += lds[t + off];
    __syncthreads();
  }
  int S = lds[0];
  int i = b * TPB + t;
  if (i == 0) row_ptr[0] = 0;
  if (i < NN) row_ptr[i + 1] = incl[i] + S;
}

// LDS-free atomic-free fill + embed at full occupancy (r14 structure).
__global__ __launch_bounds__(TPB) void k_fill_embed(
    const int* __restrict__ src, const int* __restrict__ dst,
    const unsigned* __restrict__ partial, const unsigned char* __restrict__ rank8,
    const int* __restrict__ row_ptr, unsigned short* __restrict__ srcs,
    const int* __restrict__ x, const float* __restrict__ emb,
    unsigned* __restrict__ h_bf) {
  int b = blockIdx.x;
  if (b < EDGE_BLKS) {
    int e = b * TPB + threadIdx.x;
    int d = dst[e];
    int bh = e / HIST_EPB;
    unsigned base = (partial[(size_t)bh * HIST_WORDS + (d >> 2)] >> (8u * (d & 3))) & 255u;
    int pos = row_ptr[d] + (int)base + (int)rank8[e];
    srcs[pos] = (unsigned short)src[e];
  } else {
    int i = (b - EDGE_BLKS) * TPB + threadIdx.x;  // < NN*32 exactly
    int n = i >> 5, l = i & 31;
    float2 ev = *(const float2*)&emb[x[n] * 64 + 2 * l];
    h_bf[i] = f2bf(ev.x) | (f2bf(ev.y) << 16);
  }
}

// Aggregate over bf16 h, optional BN affine folded in -> packed bf16.
// Wave per node; 32 lanes x 2 features; halves take even/odd edges.
// Clamped batch-16: always 8 gathers in flight per half-wave (indices clamped
// to end-1 -> wasted gathers L1-broadcast the same row, ~free), masked adds.
// Removes the r14 serial tail (up to 4 x ~400cy dependent round trips/node).
template <bool BN>
__global__ void k_aggregate_bf(const unsigned* __restrict__ h_bf,
                               const int* __restrict__ row_ptr,
                               const unsigned short* __restrict__ srcs,
                               const float* __restrict__ bnst,
                               unsigned* __restrict__ zb) {
  int wid = (blockIdx.x * TPB + threadIdx.x) >> 6;
  int lane = threadIdx.x & 63;
  if (wid >= NN) return;
  int half = lane >> 5, l = lane & 31;
  int beg = row_ptr[wid], end = row_ptr[wid + 1];
  float a0 = 0.f, a1 = 0.f;
  if (half == 0) {
    unsigned u = h_bf[(size_t)wid * 32 + l];
    a0 = bf2f(u & 0xFFFF);
    a1 = bf2f(u >> 16);
  }
  for (int e = beg + half; e < end; e += 16) {
    int idx[8];
#pragma unroll
    for (int k = 0; k < 8; ++k) {
      int ee = e + 2 * k;
      idx[k] = srcs[ee < end ? ee : end - 1];
    }
    unsigned uu[8];
#pragma unroll
    for (int k = 0; k < 8; ++k) uu[k] = h_bf[(size_t)idx[k] * 32 + l];
#pragma unroll
    for (int k = 0; k < 8; ++k) {
      bool v = (e + 2 * k) < end;
      a0 += v ? bf2f(uu[k] & 0xFFFF) : 0.f;
      a1 += v ? bf2f(uu[k] >> 16) : 0.f;
    }
  }
  a0 += __shfl_xor(a0, 32);
  a1 += __shfl_xor(a1, 32);
  if (half == 0) {
    float zv0, zv1;
    if constexpr (BN) {
      float2 scv = *(const float2*)&bnst[2 * l];
      float2 shv = *(const float2*)&bnst[64 + 2 * l];
      float d1 = (float)(1 + end - beg);
      zv0 = fmaf(scv.x, a0, d1 * shv.x);
      zv1 = fmaf(scv.y, a1, d1 * shv.y);
    } else {
      zv0 = a0;
      zv1 = a1;
    }
    zb[(size_t)wid * 32 + l] = f2bf(zv0) | (f2bf(zv1) << 16);
  }
}

// MFMA GEMM1: z2[N,128] = z[N,64] @ W[64,128] + b1 (bf16 in/out, f32 acc),
// per-block column stats. C/D layout: col=lane&15, row=(lane>>4)*4+reg.
__global__ __launch_bounds__(TPB) void k_gemm1(const unsigned short* __restrict__ zb,
                                               const float* __restrict__ W,
                                               const float* __restrict__ bias,
                                               unsigned short* __restrict__ z2b,
                                               float* __restrict__ partials) {
  __shared__ __align__(16) unsigned short WTl[128 * 72];  // 18KB; reused for stats
  const int t = threadIdx.x;
  const int r0 = blockIdx.x * 64;
#pragma unroll
  for (int it = 0; it < 8192 / TPB; ++it) {
    int idx = t + it * TPB;            // W row-major [64][128]: k=idx>>7, n=idx&127
    WTl[(idx & 127) * 72 + (idx >> 7)] = (unsigned short)f2bf(W[idx]);
  }
  __syncthreads();

  const int w = t >> 6, lane = t & 63;
  const int m16 = lane & 15, kg = lane >> 4;
  const int ra = r0 + w * 16 + m16;
  bf16x8 a0 = {0, 0, 0, 0, 0, 0, 0, 0}, a1 = {0, 0, 0, 0, 0, 0, 0, 0};
  if (ra < NN) {
    a0 = *(const bf16x8*)&zb[(size_t)ra * 64 + kg * 8];
    a1 = *(const bf16x8*)&zb[(size_t)ra * 64 + 32 + kg * 8];
  }
  f32x4 acc[8];
#pragma unroll
  for (int f = 0; f < 8; ++f) acc[f] = f32x4{0.f, 0.f, 0.f, 0.f};
#pragma unroll
  for (int f = 0; f < 8; ++f) {
    bf16x8 b0 = *(const bf16x8*)&WTl[(f * 16 + m16) * 72 + kg * 8];
    bf16x8 b1 = *(const bf16x8*)&WTl[(f * 16 + m16) * 72 + 32 + kg * 8];
    acc[f] = __builtin_amdgcn_mfma_f32_16x16x32_bf16(a0, b0, acc[f], 0, 0, 0);
    acc[f] = __builtin_amdgcn_mfma_f32_16x16x32_bf16(a1, b1, acc[f], 0, 0, 0);
  }
  __syncthreads();  // WTl no longer needed; reuse as stats scratch
  float* Ss = (float*)WTl;   // [4][128]
  float* Sq = Ss + 512;      // [4][128]
  const int rwb = r0 + w * 16 + kg * 4;
#pragma unroll
  for (int f = 0; f < 8; ++f) {
    int col = f * 16 + m16;
    float bc = bias[col];
    float cs = 0.f, cq = 0.f;
#pragma unroll
    for (int j = 0; j < 4; ++j) {
      int rw = rwb + j;
      if (rw < NN) {
        float v = acc[f][j] + bc;
        z2b[(size_t)rw * 128 + col] = (unsigned short)f2bf(v);
        cs += v;
        cq += v * v;
      }
    }
    cs += __shfl_xor(cs, 16); cs += __shfl_xor(cs, 32);
    cq += __shfl_xor(cq, 16); cq += __shfl_xor(cq, 32);
    if (kg == 0) {
      Ss[w * 128 + col] = cs;
      Sq[w * 128 + col] = cq;
    }
  }
  __syncthreads();
  if (t < 128) {
    float ss = Ss[t] + Ss[128 + t] + Ss[256 + t] + Ss[384 + t];
    float qq = Sq[t] + Sq[128 + t] + Sq[256 + t] + Sq[384 + t];
    partials[blockIdx.x * 256 + t] = ss;
    partials[blockIdx.x * 256 + 128 + t] = qq;
  }
}

// MFMA GEMM2: h[N,64] = relu( relu(bn1(z2)) @ W[128,64] + b2 ), bf16 in/out.
template <bool STATS>
__global__ __launch_bounds__(TPB) void k_gemm2(const unsigned short* __restrict__ z2b,
                                               const float* __restrict__ W,
                                               const float* __restrict__ bias,
                                               const float* __restrict__ bnst,
                                               unsigned short* __restrict__ outp,
                                               float* __restrict__ partials) {
  __shared__ __align__(16) unsigned short WTl[64 * 136];  // 17.4KB; reused for stats
  __shared__ float scl[128], shl[128];
  const int t = threadIdx.x;
  const int r0 = blockIdx.x * 64;
#pragma unroll
  for (int it = 0; it < 8192 / TPB; ++it) {
    int idx = t + it * TPB;            // W row-major [128][64]: k=idx>>6, n=idx&63
    WTl[(idx & 63) * 136 + (idx >> 6)] = (unsigned short)f2bf(W[idx]);
  }
  if (t < 128) {
    scl[t] = bnst[t];
    shl[t] = bnst[128 + t];
  }
  __syncthreads();

  const int w = t >> 6, lane = t & 63;
  const int m16 = lane & 15, kg = lane >> 4;
  const int ra = r0 + w * 16 + m16;
  f32x4 acc[4];
#pragma unroll
  for (int f = 0; f < 4; ++f) acc[f] = f32x4{0.f, 0.f, 0.f, 0.f};
#pragma unroll
  for (int s = 0; s < 4; ++s) {
    int k0 = s * 32 + kg * 8;
    bf16x8 a = {0, 0, 0, 0, 0, 0, 0, 0};
    if (ra < NN) {
      bf16x8 raw = *(const bf16x8*)&z2b[(size_t)ra * 128 + k0];
#pragma unroll
      for (int i = 0; i < 8; ++i) {
        float v = bf2f((unsigned)(unsigned short)raw[i]);
        v = fmaxf(fmaf(v, scl[k0 + i], shl[k0 + i]), 0.f);
        a[i] = (short)f2bf(v);
      }
    }
#pragma unroll
    for (int f = 0; f < 4; ++f) {
      bf16x8 b = *(const bf16x8*)&WTl[(f * 16 + m16) * 136 + k0];
      acc[f] = __builtin_amdgcn_mfma_f32_16x16x32_bf16(a, b, acc[f], 0, 0, 0);
    }
  }
  __syncthreads();
  float* Ss = (float*)WTl;  // [4][64]
  float* Sq = Ss + 256;
  const int rwb = r0 + w * 16 + kg * 4;
#pragma unroll
  for (int f = 0; f < 4; ++f) {
    int col = f * 16 + m16;
    float bc = bias[col];
    float cs = 0.f, cq = 0.f;
#pragma unroll
    for (int j = 0; j < 4; ++j) {
      int rw = rwb + j;
      if (rw < NN) {
        float v = fmaxf(acc[f][j] + bc, 0.f);
        outp[(size_t)rw * 64 + col] = (unsigned short)f2bf(v);
        if constexpr (STATS) {
          cs += v;
          cq += v * v;
        }
      }
    }
    if constexpr (STATS) {
      cs += __shfl_xor(cs, 16); cs += __shfl_xor(cs, 32);
      cq += __shfl_xor(cq, 16); cq += __shfl_xor(cq, 32);
      if (kg == 0) {
        Ss[w * 64 + col] = cs;
        Sq[w * 64 + col] = cq;
      }
    }
  }
  if constexpr (STATS) {
    __syncthreads();
    if (t < 64) {
      float ss = Ss[t] + Ss[64 + t] + Ss[128 + t] + Ss[192 + t];
      float qq = Sq[t] + Sq[64 + t] + Sq[128 + t] + Sq[192 + t];
      partials[blockIdx.x * 128 + t] = ss;
      partials[blockIdx.x * 128 + 64 + t] = qq;
    }
  }
}

// Fold partials: constant trip count + unroll-8 (r8 fix), LDS tree-fold.
// 1024 threads (r15): halves the per-dispatch latency of these 7 serialized
// critical-path kernels.
template <int C>
__global__ __launch_bounds__(TPB_FIN) void k_finalize(const float* __restrict__ partials,
                                                      const float* __restrict__ gamma,
                                                      const float* __restrict__ beta,
                                                      float* __restrict__ out) {
  constexpr int G = TPB_FIN / C;
  constexpr int IT = NBLK_G / G;
  __shared__ float lds[2 * TPB_FIN];
  const int c = threadIdx.x % C, g = threadIdx.x / C;
  const float* p = partials + g * 2 * C + c;
  float s = 0.f, s2 = 0.f;
#pragma unroll 8
  for (int bb = 0; bb < IT; ++bb) {
    s += p[(size_t)bb * G * 2 * C];
    s2 += p[(size_t)bb * G * 2 * C + C];
  }
  lds[threadIdx.x] = s;
  lds[TPB_FIN + threadIdx.x] = s2;
  __syncthreads();
  if (g == 0) {
#pragma unroll
    for (int k = 1; k < G; ++k) {
      s += lds[k * C + c];
      s2 += lds[TPB_FIN + k * C + c];
    }
    float invN = 1.0f / NN;
    float mu = s * invN;
    float var = s2 * invN - mu * mu;
    float rs = rsqrtf(var + BN_EPS) * gamma[c];
    out[c] = rs;
    out[C + c] = beta[c] - mu * rs;
  }
}

// Fused pool + head: block per graph.
__global__ void k_poolhead(const unsigned* __restrict__ h_bf,
                           const int* __restrict__ batch,
                           const float* __restrict__ Wh1, const float* __restrict__ bh1,
                           const float* __restrict__ Wh2, const float* __restrict__ bh2,
                           float* __restrict__ out) {
  __shared__ float lds[2 * TPB];
  __shared__ float gl[64];
  __shared__ float hidl[32];
  int gi = blockIdx.x;
  int col = threadIdx.x & 31, grp = threadIdx.x >> 5;
  int a = 0, b = NN;
  while (a < b) { int m = (a + b) >> 1; if (batch[m] < gi) a = m + 1; else b = m; }
  int lo = a;
  b = NN;
  while (a < b) { int m = (a + b) >> 1; if (batch[m] < gi + 1) a = m + 1; else b = m; }
  int hi = a;
  float a0 = 0.f, a1 = 0.f;
  for (int n = lo + grp; n < hi; n += 8) {
    unsigned u = h_bf[(size_t)n * 32 + col];
    a0 += bf2f(u & 0xFFFF);
    a1 += bf2f(u >> 16);
  }
  lds[threadIdx.x] = a0;
  lds[TPB + threadIdx.x] = a1;
  __syncthreads();
  if (grp == 0) {
#pragma unroll
    for (int k = 1; k < 8; ++k) {
      a0 += lds[k * 32 + col];
      a1 += lds[TPB + k * 32 + col];
    }
    gl[2 * col] = a0;
    gl[2 * col + 1] = a1;
  }
  __syncthreads();
  if (threadIdx.x < 32) {
    int j = threadIdx.x;
    float hid = bh1[j];
    for (int k = 0; k < 64; ++k) hid = fmaf(gl[k], Wh1[k * 32 + j], hid);
    hidl[j] = fmaxf(hid, 0.f);
  }
  __syncthreads();
  if (threadIdx.x < 10) {
    int j = threadIdx.x;
    float o = bh2[j];
#pragma unroll
    for (int k = 0; k < 32; ++k) o = fmaf(hidl[k], Wh2[k * 10 + j], o);
    out[gi * 10 + j] = o;
  }
}

extern "C" void kernel_launch(void* const* d_in, const int* in_sizes, int n_in,
                              void* d_out, int out_size, void* d_ws, size_t ws_size,
                              hipStream_t stream) {
  const int* x = (const int*)d_in[0];
  const int* ei = (const int*)d_in[1];
  const int* batch = (const int*)d_in[2];
  const float* emb = (const float*)d_in[3];
  const float* W1 = (const float*)d_in[4];
  const float* b1 = (const float*)d_in[5];
  const float* g1 = (const float*)d_in[6];
  const float* bt1 = (const float*)d_in[7];
  const float* W2 = (const float*)d_in[8];
  const float* b2 = (const float*)d_in[9];
  const float* gbn = (const float*)d_in[10];
  const float* bbn = (const float*)d_in[11];
  const float* Wh1 = (const float*)d_in[12];
  const float* bh1 = (const float*)d_in[13];
  const float* Wh2 = (const float*)d_in[14];
  const float* bh2 = (const float*)d_in[15];
  float* out = (float*)d_out;

  const int* e_src = ei;
  const int* e_dst = ei + NE;

  char* ws = (char*)d_ws;
  size_t off = 0;
  auto alloc = [&](size_t bytes) -> void* {
    void* p = ws + off;
    off = (off + bytes + 255) & ~(size_t)255;
    return p;
  };
  unsigned* h_bf = (unsigned*)alloc((size_t)NN * 64 * 2);
  unsigned* zb = (unsigned*)alloc((size_t)NN * 64 * 2);
  unsigned short* z2b = (unsigned short*)alloc((size_t)NN * 128 * 2);
  unsigned short* srcs = (unsigned short*)alloc((size_t)NE * 2);
  unsigned char* rank8 = (unsigned char*)alloc((size_t)NE);
  int* row_ptr = (int*)alloc((size_t)(NN + 1) * 4);
  int* incl = (int*)alloc((size_t)NN * 4);
  int* btot = (int*)alloc(256 * 4);
  float* partials = (float*)alloc((size_t)NBLK_G * 256 * 4);
  float* statsL = (float*)alloc(4 * 256 * 4);
  float* statsH = (float*)alloc(3 * 128 * 4);
  int* counts = (int*)alloc((size_t)NN * 4);
  unsigned* histpart = (unsigned*)alloc((size_t)HIST_BLKS * HIST_WORDS * 4);

  k_hist_lds<<<HIST_BLKS, TPB, 0, stream>>>(e_dst, histpart, rank8);
  k_hist_scan<<<(HIST_WORDS + TPB - 1) / TPB, TPB, 0, stream>>>(histpart, counts);

  int nScanBlocks = (NN + TPB - 1) / TPB;  // 196
  k_scan1<<<nScanBlocks, TPB, 0, stream>>>(counts, incl, btot);
  k_scan23<<<nScanBlocks, TPB, 0, stream>>>(incl, btot, row_ptr);
  k_fill_embed<<<EDGE_BLKS + EMB_BLKS, TPB, 0, stream>>>(e_src, e_dst, histpart, rank8,
                                                         row_ptr, srcs, x, emb, h_bf);

  int gAgg = (NN * 64 + TPB - 1) / TPB;  // 12500 (wave per node)

  for (int i = 0; i < 4; ++i) {
    const float* W1i = W1 + (size_t)i * 64 * 128;
    const float* b1i = b1 + (size_t)i * 128;
    const float* g1i = g1 + (size_t)i * 128;
    const float* bt1i = bt1 + (size_t)i * 128;
    const float* W2i = W2 + (size_t)i * 128 * 64;
    const float* b2i = b2 + (size_t)i * 64;
    float* stL = statsL + (size_t)i * 256;

    if (i == 0)
      k_aggregate_bf<false><<<gAgg, TPB, 0, stream>>>(h_bf, row_ptr, srcs, nullptr, zb);
    else
      k_aggregate_bf<true><<<gAgg, TPB, 0, stream>>>(h_bf, row_ptr, srcs,
                                                     statsH + (size_t)(i - 1) * 128, zb);

    k_gemm1<<<NBLK_G, TPB, 0, stream>>>((const unsigned short*)zb, W1i, b1i, z2b, partials);
    k_finalize<128><<<1, TPB_FIN, 0, stream>>>(partials, g1i, bt1i, stL);

    if (i < 3) {
      float* stH = statsH + (size_t)i * 128;
      k_gemm2<true><<<NBLK_G, TPB, 0, stream>>>(z2b, W2i, b2i, stL,
                                                (unsigned short*)h_bf, partials);
      k_finalize<64><<<1, TPB_FIN, 0, stream>>>(partials, gbn + (size_t)i * 64,
                                                bbn + (size_t)i * 64, stH);
    } else {
      k_gemm2<false><<<NBLK_G, TPB, 0, stream>>>(z2b, W2i, b2i, stL,
                                                 (unsigned short*)h_bf, partials);
    }
  }

  k_poolhead<<<NG, TPB, 0, stream>>>(h_bf, batch, Wh1, bh1, Wh2, bh2, out);
}